// Round 1
// baseline (560.352 us; speedup 1.0000x reference)
//
#include <hip/hip_runtime.h>
#include <hip/hip_bf16.h>

#define NTOT 3145728   // 256*3*64*64
#define NIMG 768       // 256*3
#define CTAPS 1024     // GL conv truncation
#define COUT 2048      // conv outputs per block

// ---------------------------------------------------------------- tables ----
__global__ __launch_bounds__(1024)
void gen_tables(float* __restrict__ Tc, float* __restrict__ Ts, float* __restrict__ w)
{
    const int tid = threadIdx.x;
    const float step = 6.28318530717958647692f / 64.0f;
    for (int i = tid; i < 4096; i += 1024) {
        int p = i >> 6, q = i & 63;
        float ang = (float)((p * q) & 63) * step;
        Tc[i] = cosf(ang);
        Ts[i] = sinf(ang);
    }
    // w[j] = h^{-alpha} * cumprod_{i=1..j} ((i-1-0.5)/i), matching reference f32 order
    float prod = 1.0f;
    for (int i = 1; i <= tid; ++i)
        prod *= (((float)i - 1.0f) - 0.5f) / (float)i;
    w[tid] = prod * sqrtf((float)(NTOT - 1));
}

// ---------------------------------------------------------------- GEMM ------
// P[z][m][n] = sum_{k in chunk z} A[m][k]*W[k][n].  64x64 tile, 4x4 micro.
__global__ __launch_bounds__(256)
void gemm_f32(const float* __restrict__ A, const float* __restrict__ W,
              float* __restrict__ P, int M, int N, int K, int kChunk)
{
    __shared__ __align__(16) float As[16][68];
    __shared__ __align__(16) float Bs[16][68];
    const int tid = threadIdx.x;
    const int bm = blockIdx.x * 64;
    const int bn = blockIdx.y * 64;
    const int z  = blockIdx.z;
    const int k0 = z * kChunk;
    const int k1 = k0 + kChunk;
    const int tx = tid & 15, ty = tid >> 4;
    const int la_c = tid & 15, la_r = tid >> 4;   // A: 16 cols x 16 rows/pass
    const int lb_c = tid & 63, lb_r = tid >> 6;   // B: 64 cols x 4 rows/pass
    float acc[4][4] = {};
    for (int kb = k0; kb < k1; kb += 16) {
        #pragma unroll
        for (int i = 0; i < 4; ++i) {
            int r = la_r + i * 16;
            As[la_c][r] = A[(size_t)(bm + r) * K + (kb + la_c)];
        }
        #pragma unroll
        for (int i = 0; i < 4; ++i) {
            int r = lb_r + i * 4;
            Bs[r][lb_c] = W[(size_t)(kb + r) * N + (bn + lb_c)];
        }
        __syncthreads();
        #pragma unroll
        for (int kk = 0; kk < 16; ++kk) {
            float4 av = *(const float4*)&As[kk][ty * 4];
            float4 bv = *(const float4*)&Bs[kk][tx * 4];
            float a_[4] = {av.x, av.y, av.z, av.w};
            float b_[4] = {bv.x, bv.y, bv.z, bv.w};
            #pragma unroll
            for (int i = 0; i < 4; ++i)
                #pragma unroll
                for (int j = 0; j < 4; ++j)
                    acc[i][j] = fmaf(a_[i], b_[j], acc[i][j]);
        }
        __syncthreads();
    }
    float* Pp = P + (size_t)z * M * N;
    #pragma unroll
    for (int i = 0; i < 4; ++i) {
        float4 v = {acc[i][0], acc[i][1], acc[i][2], acc[i][3]};
        *(float4*)&Pp[(size_t)(bm + ty * 4 + i) * N + bn + tx * 4] = v;
    }
}

// ------------------------------------------------------------- col pass -----
// out[p][q] = scale * sum_m ( Tc[p][m]*C[m][q] - Ts[p][m]*S[m][q] ), per image.
// Tc/Ts symmetric, so Tc[p][m] is read as row-major Tc[m][p0..p0+3].
__global__ __launch_bounds__(256)
void colpass(const float* Ca, const float* Sa,
             const float* __restrict__ Tc, const float* __restrict__ Ts,
             float* out, float scale)
{
    __shared__ __align__(16) float Cs[64][68];
    __shared__ __align__(16) float Sh[64][68];
    const int tid = threadIdx.x;
    const int img = blockIdx.x;
    const float4* C4 = (const float4*)(Ca + (size_t)img * 4096);
    const float4* S4 = (const float4*)(Sa + (size_t)img * 4096);
    #pragma unroll
    for (int i = 0; i < 4; ++i) {
        int li = tid + i * 256;           // 0..1023 float4s
        int row = li >> 4, col = (li & 15) * 4;
        *(float4*)&Cs[row][col] = C4[li];
        *(float4*)&Sh[row][col] = S4[li];
    }
    __syncthreads();
    const int tx = tid & 15, ty = tid >> 4;
    const int p0 = ty * 4, q0 = tx * 4;
    float acc[4][4] = {};
    for (int m = 0; m < 64; ++m) {
        float4 a  = *(const float4*)&Tc[m * 64 + p0];
        float4 at = *(const float4*)&Ts[m * 64 + p0];
        float4 c  = *(const float4*)&Cs[m][q0];
        float4 s  = *(const float4*)&Sh[m][q0];
        float a_[4]  = {a.x, a.y, a.z, a.w};
        float at_[4] = {at.x, at.y, at.z, at.w};
        float c_[4]  = {c.x, c.y, c.z, c.w};
        float s_[4]  = {s.x, s.y, s.z, s.w};
        #pragma unroll
        for (int i = 0; i < 4; ++i)
            #pragma unroll
            for (int j = 0; j < 4; ++j)
                acc[i][j] += a_[i] * c_[j] - at_[i] * s_[j];
    }
    float* o = out + (size_t)img * 4096;
    #pragma unroll
    for (int i = 0; i < 4; ++i) {
        float4 v = {acc[i][0] * scale, acc[i][1] * scale,
                    acc[i][2] * scale, acc[i][3] * scale};
        *(float4*)&o[(p0 + i) * 64 + q0] = v;
    }
}

// ---------------------------------------------------------------- conv ------
// fr[k] = sum_{j=0}^{1023} w[j] * f[k-j]   (f[<0] = 0); w already scaled.
__global__ __launch_bounds__(256)
void conv_gl(const float* __restrict__ f, const float* __restrict__ w,
             float* __restrict__ fr)
{
    __shared__ __align__(16) float fs[COUT + CTAPS + 8];   // 3080 floats
    const int tid = threadIdx.x;
    const long long k0 = (long long)blockIdx.x * COUT;
    const long long base = k0 - (CTAPS + 8);
    for (int i = tid; i < COUT + CTAPS + 8; i += 256) {
        long long g = base + i;
        fs[i] = (g >= 0) ? f[g] : 0.0f;
    }
    __syncthreads();
    const int sl = tid * 8 + CTAPS + 8;   // fs index of this thread's first output
    float acc[8] = {0, 0, 0, 0, 0, 0, 0, 0};
    float win[16];                        // win[i] = f[s - j0 - 8 + i]
    #pragma unroll
    for (int i = 0; i < 16; ++i) win[i] = fs[sl - 8 + i];
    for (int j0 = 0; j0 < CTAPS; j0 += 8) {
        float wv[8];
        #pragma unroll
        for (int jj = 0; jj < 8; ++jj) wv[jj] = w[j0 + jj];   // wave-uniform -> s_load
        #pragma unroll
        for (int jj = 0; jj < 8; ++jj)
            #pragma unroll
            for (int o = 0; o < 8; ++o)
                acc[o] = fmaf(wv[jj], win[8 + o - jj], acc[o]);
        if (j0 + 8 < CTAPS) {
            float nw[8];
            #pragma unroll
            for (int i = 0; i < 8; ++i) nw[i] = fs[sl - j0 - 16 + i];
            #pragma unroll
            for (int i = 0; i < 8; ++i) win[8 + i] = win[i];
            #pragma unroll
            for (int i = 0; i < 8; ++i) win[i] = nw[i];
        }
    }
    float* dst = fr + k0 + tid * 8;
    float4 v0 = {acc[0], acc[1], acc[2], acc[3]};
    float4 v1 = {acc[4], acc[5], acc[6], acc[7]};
    *(float4*)&dst[0] = v0;
    *(float4*)&dst[4] = v1;
}

// --------------------------------------------------------------- reduce -----
__global__ __launch_bounds__(256)
void reduce_bias(const float* __restrict__ P, const float* __restrict__ bias,
                 float* __restrict__ C, int MN, int N, int S, int relu)
{
    const int idx4 = blockIdx.x * 256 + threadIdx.x;
    const int MN4 = MN >> 2;
    if (idx4 >= MN4) return;
    const float4* P4 = (const float4*)P;
    float4 a = P4[idx4];
    for (int z = 1; z < S; ++z) {
        float4 b = P4[(size_t)z * MN4 + idx4];
        a.x += b.x; a.y += b.y; a.z += b.z; a.w += b.w;
    }
    int n0 = (idx4 * 4) % N;
    a.x += bias[n0]; a.y += bias[n0 + 1]; a.z += bias[n0 + 2]; a.w += bias[n0 + 3];
    if (relu) {
        a.x = fmaxf(a.x, 0.f); a.y = fmaxf(a.y, 0.f);
        a.z = fmaxf(a.z, 0.f); a.w = fmaxf(a.w, 0.f);
    }
    ((float4*)C)[idx4] = a;
}

// ---------------------------------------------------------------- launch ----
extern "C" void kernel_launch(void* const* d_in, const int* in_sizes, int n_in,
                              void* d_out, int out_size, void* d_ws, size_t ws_size,
                              hipStream_t stream)
{
    const float* x   = (const float*)d_in[0];
    const float* Ws1 = (const float*)d_in[1];
    const float* bs1 = (const float*)d_in[2];
    const float* Ws2 = (const float*)d_in[3];
    const float* bs2 = (const float*)d_in[4];
    const float* Wn1 = (const float*)d_in[5];
    const float* bn1 = (const float*)d_in[6];
    const float* Wn2 = (const float*)d_in[7];
    const float* bn2 = (const float*)d_in[8];
    const float* Wn3 = (const float*)d_in[9];
    const float* bn3 = (const float*)d_in[10];
    float* out = (float*)d_out;

    float* ws = (float*)d_ws;
    size_t off = 0;
    float* Tc   = ws + off; off += 4096;
    float* Ts   = ws + off; off += 4096;
    float* wgl  = ws + off; off += 1024;
    off = (off + 63) & ~(size_t)63;
    float* t1   = ws + off; off += 131072;        // (256,512)
    float* h1   = ws + off; off += 131072;
    float* h2   = ws + off; off += 131072;
    float* part = ws + off; off += 8 * 131072;    // split-K partials
    float* bufA = ws + off; off += NTOT;
    float* bufB = ws + off; off += NTOT;
    float* bufC = ws + off; off += NTOT;          // ~43.5 MB total

    gen_tables<<<1, 1024, 0, stream>>>(Tc, Ts, wgl);

    // forward fft2 real part: row pass (one GEMM per table), then col pass
    gemm_f32<<<dim3(768, 1, 1), 256, 0, stream>>>(x, Tc, bufA, 49152, 64, 64, 64);
    gemm_f32<<<dim3(768, 1, 1), 256, 0, stream>>>(x, Ts, bufB, 49152, 64, 64, 64);
    colpass<<<NIMG, 256, 0, stream>>>(bufA, bufB, Tc, Ts, bufA, 1.0f);  // f -> bufA

    // GL fractional conv over the flat 3.1M signal
    conv_gl<<<NTOT / COUT, 256, 0, stream>>>(bufA, wgl, bufB);          // fr -> bufB

    // spectral_operator: Linear(12288->512) ReLU Linear(512->12288)
    gemm_f32<<<dim3(4, 8, 8), 256, 0, stream>>>(bufB, Ws1, part, 256, 512, 12288, 1536);
    reduce_bias<<<128, 256, 0, stream>>>(part, bs1, t1, 131072, 512, 8, 1);
    gemm_f32<<<dim3(4, 192, 1), 256, 0, stream>>>(t1, Ws2, bufA, 256, 12288, 512, 512);
    reduce_bias<<<3072, 256, 0, stream>>>(bufA, bs2, bufA, NTOT, 12288, 1, 0);  // spec

    // neural_operator: 12288->512 ReLU 512->512 ReLU 512->12288
    gemm_f32<<<dim3(4, 8, 8), 256, 0, stream>>>(bufA, Wn1, part, 256, 512, 12288, 1536);
    reduce_bias<<<128, 256, 0, stream>>>(part, bn1, h1, 131072, 512, 8, 1);
    gemm_f32<<<dim3(4, 8, 4), 256, 0, stream>>>(h1, Wn2, part, 256, 512, 512, 128);
    reduce_bias<<<128, 256, 0, stream>>>(part, bn2, h2, 131072, 512, 4, 1);
    gemm_f32<<<dim3(4, 192, 1), 256, 0, stream>>>(h2, Wn3, bufA, 256, 12288, 512, 512);
    reduce_bias<<<3072, 256, 0, stream>>>(bufA, bn3, bufA, NTOT, 12288, 1, 0);  // proc

    // inverse fft2 real part (scale 1/4096)
    gemm_f32<<<dim3(768, 1, 1), 256, 0, stream>>>(bufA, Tc, bufB, 49152, 64, 64, 64);
    gemm_f32<<<dim3(768, 1, 1), 256, 0, stream>>>(bufA, Ts, bufC, 49152, 64, 64, 64);
    colpass<<<NIMG, 256, 0, stream>>>(bufB, bufC, Tc, Ts, out, 1.0f / 4096.0f);
}

// Round 2
// 542.529 us; speedup vs baseline: 1.0329x; 1.0329x over previous
//
#include <hip/hip_runtime.h>
#include <hip/hip_bf16.h>

#define NTOT 3145728   // 256*3*64*64
#define NIMG 768       // 256*3
#define CTAPS 1024     // GL conv truncation
#define COUT 2048      // conv outputs per block

// ---------------------------------------------------------------- tables ----
__global__ __launch_bounds__(1024)
void gen_tables(float* __restrict__ Tc, float* __restrict__ Ts, float* __restrict__ w)
{
    const int tid = threadIdx.x;
    const float step = 6.28318530717958647692f / 64.0f;
    for (int i = tid; i < 4096; i += 1024) {
        int p = i >> 6, q = i & 63;
        float ang = (float)((p * q) & 63) * step;
        Tc[i] = cosf(ang);
        Ts[i] = sinf(ang);
    }
    // w[j] = h^{-alpha} * cumprod_{i=1..j} ((i-1-0.5)/i), matching reference f32 order
    float prod = 1.0f;
    for (int i = 1; i <= tid; ++i)
        prod *= (((float)i - 1.0f) - 0.5f) / (float)i;
    w[tid] = prod * sqrtf((float)(NTOT - 1));
}

// ---------------------------------------------------------- fused 2-D DFT ---
// One block per 64x64 image.
//   row pass: C[r][q] = sum_m X[r][m]*Tc[m][q],  S[r][q] = sum_m X[r][m]*Ts[m][q]
//   col pass: out[p][q] = scale * sum_m ( Tc[m][p]*C[m][q] - Ts[m][p]*S[m][q] )
// (Tc/Ts symmetric; identical math/order to the validated round-1 pipeline.)
__global__ __launch_bounds__(256)
void dft2_real(const float* __restrict__ X, const float* __restrict__ Tc,
               const float* __restrict__ Ts, float* __restrict__ out, float scale)
{
    __shared__ float Xs[64 * 65];                 // stride 65: 2-way max on reads
    __shared__ __align__(16) float Cs[64][68];
    __shared__ __align__(16) float Ss[64][68];
    const int tid = threadIdx.x;
    const int img = blockIdx.x;

    const float4* X4 = (const float4*)(X + (size_t)img * 4096);
    #pragma unroll
    for (int i = 0; i < 4; ++i) {
        int li = tid + i * 256;                   // float4 index 0..1023
        int r = li >> 4, m0 = (li & 15) * 4;
        float4 v = X4[li];
        float* p = &Xs[r * 65 + m0];
        p[0] = v.x; p[1] = v.y; p[2] = v.z; p[3] = v.w;
    }
    __syncthreads();

    const int tx = tid & 15, ty = tid >> 4;
    const int p0 = ty * 4, q0 = tx * 4;

    float c[4][4] = {}, s[4][4] = {};
    for (int m = 0; m < 64; ++m) {
        float4 tcv = *(const float4*)&Tc[m * 64 + q0];
        float4 tsv = *(const float4*)&Ts[m * 64 + q0];
        float tc_[4] = {tcv.x, tcv.y, tcv.z, tcv.w};
        float ts_[4] = {tsv.x, tsv.y, tsv.z, tsv.w};
        float a_[4];
        #pragma unroll
        for (int i = 0; i < 4; ++i) a_[i] = Xs[(p0 + i) * 65 + m];
        #pragma unroll
        for (int i = 0; i < 4; ++i)
            #pragma unroll
            for (int j = 0; j < 4; ++j) {
                c[i][j] = fmaf(a_[i], tc_[j], c[i][j]);
                s[i][j] = fmaf(a_[i], ts_[j], s[i][j]);
            }
    }
    #pragma unroll
    for (int i = 0; i < 4; ++i) {
        float4 cv = {c[i][0], c[i][1], c[i][2], c[i][3]};
        float4 sv = {s[i][0], s[i][1], s[i][2], s[i][3]};
        *(float4*)&Cs[p0 + i][q0] = cv;
        *(float4*)&Ss[p0 + i][q0] = sv;
    }
    __syncthreads();

    float acc[4][4] = {};
    for (int m = 0; m < 64; ++m) {
        float4 tcv = *(const float4*)&Tc[m * 64 + p0];
        float4 tsv = *(const float4*)&Ts[m * 64 + p0];
        float4 cv  = *(const float4*)&Cs[m][q0];
        float4 sv  = *(const float4*)&Ss[m][q0];
        float tc_[4] = {tcv.x, tcv.y, tcv.z, tcv.w};
        float ts_[4] = {tsv.x, tsv.y, tsv.z, tsv.w};
        float c_[4]  = {cv.x, cv.y, cv.z, cv.w};
        float s_[4]  = {sv.x, sv.y, sv.z, sv.w};
        #pragma unroll
        for (int i = 0; i < 4; ++i)
            #pragma unroll
            for (int j = 0; j < 4; ++j)
                acc[i][j] += tc_[i] * c_[j] - ts_[i] * s_[j];
    }
    float* o = out + (size_t)img * 4096;
    #pragma unroll
    for (int i = 0; i < 4; ++i) {
        float4 v = {acc[i][0] * scale, acc[i][1] * scale,
                    acc[i][2] * scale, acc[i][3] * scale};
        *(float4*)&o[(p0 + i) * 64 + q0] = v;
    }
}

// ---------------------------------------------------------------- GEMM ------
// P[z][m][n] = sum_{k in chunk z} A[m][k]*W[k][n].  64x64 tile, 4x4 micro.
__global__ __launch_bounds__(256)
void gemm_f32(const float* __restrict__ A, const float* __restrict__ W,
              float* __restrict__ P, int M, int N, int K, int kChunk)
{
    __shared__ __align__(16) float As[16][68];
    __shared__ __align__(16) float Bs[16][68];
    const int tid = threadIdx.x;
    const int bm = blockIdx.x * 64;
    const int bn = blockIdx.y * 64;
    const int z  = blockIdx.z;
    const int k0 = z * kChunk;
    const int k1 = k0 + kChunk;
    const int tx = tid & 15, ty = tid >> 4;
    const int la_c = tid & 15, la_r = tid >> 4;   // A: 16 cols x 16 rows/pass
    const int lb_c = tid & 63, lb_r = tid >> 6;   // B: 64 cols x 4 rows/pass
    float acc[4][4] = {};
    for (int kb = k0; kb < k1; kb += 16) {
        #pragma unroll
        for (int i = 0; i < 4; ++i) {
            int r = la_r + i * 16;
            As[la_c][r] = A[(size_t)(bm + r) * K + (kb + la_c)];
        }
        #pragma unroll
        for (int i = 0; i < 4; ++i) {
            int r = lb_r + i * 4;
            Bs[r][lb_c] = W[(size_t)(kb + r) * N + (bn + lb_c)];
        }
        __syncthreads();
        #pragma unroll
        for (int kk = 0; kk < 16; ++kk) {
            float4 av = *(const float4*)&As[kk][ty * 4];
            float4 bv = *(const float4*)&Bs[kk][tx * 4];
            float a_[4] = {av.x, av.y, av.z, av.w};
            float b_[4] = {bv.x, bv.y, bv.z, bv.w};
            #pragma unroll
            for (int i = 0; i < 4; ++i)
                #pragma unroll
                for (int j = 0; j < 4; ++j)
                    acc[i][j] = fmaf(a_[i], b_[j], acc[i][j]);
        }
        __syncthreads();
    }
    float* Pp = P + (size_t)z * M * N;
    #pragma unroll
    for (int i = 0; i < 4; ++i) {
        float4 v = {acc[i][0], acc[i][1], acc[i][2], acc[i][3]};
        *(float4*)&Pp[(size_t)(bm + ty * 4 + i) * N + bn + tx * 4] = v;
    }
}

// ---------------------------------------------------------------- conv ------
// fr[k] = sum_{j=0}^{1023} w[j] * f[k-j]   (f[<0] = 0); w already scaled.
__global__ __launch_bounds__(256)
void conv_gl(const float* __restrict__ f, const float* __restrict__ w,
             float* __restrict__ fr)
{
    __shared__ __align__(16) float fs[COUT + CTAPS + 8];   // 3080 floats
    const int tid = threadIdx.x;
    const long long k0 = (long long)blockIdx.x * COUT;
    const long long base = k0 - (CTAPS + 8);
    for (int i = tid; i < COUT + CTAPS + 8; i += 256) {
        long long g = base + i;
        fs[i] = (g >= 0) ? f[g] : 0.0f;
    }
    __syncthreads();
    const int sl = tid * 8 + CTAPS + 8;   // fs index of this thread's first output
    float acc[8] = {0, 0, 0, 0, 0, 0, 0, 0};
    float win[16];                        // win[i] = f[s - j0 - 8 + i]
    #pragma unroll
    for (int i = 0; i < 16; ++i) win[i] = fs[sl - 8 + i];
    for (int j0 = 0; j0 < CTAPS; j0 += 8) {
        float wv[8];
        #pragma unroll
        for (int jj = 0; jj < 8; ++jj) wv[jj] = w[j0 + jj];   // wave-uniform -> s_load
        #pragma unroll
        for (int jj = 0; jj < 8; ++jj)
            #pragma unroll
            for (int o = 0; o < 8; ++o)
                acc[o] = fmaf(wv[jj], win[8 + o - jj], acc[o]);
        if (j0 + 8 < CTAPS) {
            float nw[8];
            #pragma unroll
            for (int i = 0; i < 8; ++i) nw[i] = fs[sl - j0 - 16 + i];
            #pragma unroll
            for (int i = 0; i < 8; ++i) win[8 + i] = win[i];
            #pragma unroll
            for (int i = 0; i < 8; ++i) win[i] = nw[i];
        }
    }
    float* dst = fr + k0 + tid * 8;
    float4 v0 = {acc[0], acc[1], acc[2], acc[3]};
    float4 v1 = {acc[4], acc[5], acc[6], acc[7]};
    *(float4*)&dst[0] = v0;
    *(float4*)&dst[4] = v1;
}

// --------------------------------------------------------------- reduce -----
__global__ __launch_bounds__(256)
void reduce_bias(const float* __restrict__ P, const float* __restrict__ bias,
                 float* __restrict__ C, int MN, int N, int S, int relu)
{
    const int idx4 = blockIdx.x * 256 + threadIdx.x;
    const int MN4 = MN >> 2;
    if (idx4 >= MN4) return;
    const float4* P4 = (const float4*)P;
    float4 a = P4[idx4];
    for (int z = 1; z < S; ++z) {
        float4 b = P4[(size_t)z * MN4 + idx4];
        a.x += b.x; a.y += b.y; a.z += b.z; a.w += b.w;
    }
    int n0 = (idx4 * 4) % N;
    a.x += bias[n0]; a.y += bias[n0 + 1]; a.z += bias[n0 + 2]; a.w += bias[n0 + 3];
    if (relu) {
        a.x = fmaxf(a.x, 0.f); a.y = fmaxf(a.y, 0.f);
        a.z = fmaxf(a.z, 0.f); a.w = fmaxf(a.w, 0.f);
    }
    ((float4*)C)[idx4] = a;
}

// ---------------------------------------------------------------- launch ----
extern "C" void kernel_launch(void* const* d_in, const int* in_sizes, int n_in,
                              void* d_out, int out_size, void* d_ws, size_t ws_size,
                              hipStream_t stream)
{
    const float* x   = (const float*)d_in[0];
    const float* Ws1 = (const float*)d_in[1];
    const float* bs1 = (const float*)d_in[2];
    const float* Ws2 = (const float*)d_in[3];
    const float* bs2 = (const float*)d_in[4];
    const float* Wn1 = (const float*)d_in[5];
    const float* bn1 = (const float*)d_in[6];
    const float* Wn2 = (const float*)d_in[7];
    const float* bn2 = (const float*)d_in[8];
    const float* Wn3 = (const float*)d_in[9];
    const float* bn3 = (const float*)d_in[10];
    float* out = (float*)d_out;

    float* ws = (float*)d_ws;
    size_t off = 0;
    float* Tc   = ws + off; off += 4096;
    float* Ts   = ws + off; off += 4096;
    float* wgl  = ws + off; off += 1024;
    off = (off + 63) & ~(size_t)63;
    float* t1   = ws + off; off += 131072;        // (256,512)
    float* h1   = ws + off; off += 131072;
    float* h2   = ws + off; off += 131072;
    float* part = ws + off; off += 8 * 131072;    // split-K partials
    float* bufA = ws + off; off += NTOT;
    float* bufB = ws + off; off += NTOT;

    gen_tables<<<1, 1024, 0, stream>>>(Tc, Ts, wgl);

    // forward fft2 real part, fused (row pass + col pass in one kernel)
    dft2_real<<<NIMG, 256, 0, stream>>>(x, Tc, Ts, bufA, 1.0f);          // f -> bufA

    // GL fractional conv over the flat 3.1M signal
    conv_gl<<<NTOT / COUT, 256, 0, stream>>>(bufA, wgl, bufB);           // fr -> bufB

    // spectral_operator: Linear(12288->512) ReLU Linear(512->12288)
    gemm_f32<<<dim3(4, 8, 8), 256, 0, stream>>>(bufB, Ws1, part, 256, 512, 12288, 1536);
    reduce_bias<<<128, 256, 0, stream>>>(part, bs1, t1, 131072, 512, 8, 1);
    gemm_f32<<<dim3(4, 192, 1), 256, 0, stream>>>(t1, Ws2, bufA, 256, 12288, 512, 512);
    reduce_bias<<<3072, 256, 0, stream>>>(bufA, bs2, bufA, NTOT, 12288, 1, 0);  // spec

    // neural_operator: 12288->512 ReLU 512->512 ReLU 512->12288
    gemm_f32<<<dim3(4, 8, 8), 256, 0, stream>>>(bufA, Wn1, part, 256, 512, 12288, 1536);
    reduce_bias<<<128, 256, 0, stream>>>(part, bn1, h1, 131072, 512, 8, 1);
    gemm_f32<<<dim3(4, 8, 4), 256, 0, stream>>>(h1, Wn2, part, 256, 512, 512, 128);
    reduce_bias<<<128, 256, 0, stream>>>(part, bn2, h2, 131072, 512, 4, 1);
    gemm_f32<<<dim3(4, 192, 1), 256, 0, stream>>>(h2, Wn3, bufA, 256, 12288, 512, 512);
    reduce_bias<<<3072, 256, 0, stream>>>(bufA, bn3, bufA, NTOT, 12288, 1, 0);  // proc

    // inverse fft2 real part, fused (scale 1/4096)
    dft2_real<<<NIMG, 256, 0, stream>>>(bufA, Tc, Ts, out, 1.0f / 4096.0f);
}

// Round 3
// 260.319 us; speedup vs baseline: 2.1526x; 2.0841x over previous
//
#include <hip/hip_runtime.h>
#include <hip/hip_bf16.h>

#define NTOT 3145728   // 256*3*64*64
#define NIMG 768       // 256*3
#define CTAPS 1024     // GL conv truncation
#define COUT 2048      // conv outputs per block

typedef __attribute__((ext_vector_type(8))) short bf16x8;
typedef __attribute__((ext_vector_type(8))) unsigned short u16x8;
typedef __attribute__((ext_vector_type(4))) float f32x4;

__device__ inline unsigned short f2bf(float x) {
    unsigned u = __builtin_bit_cast(unsigned, x);
    u += 0x7fffu + ((u >> 16) & 1u);
    return (unsigned short)(u >> 16);
}

// ---------------------------------------------------------------- tables ----
__global__ __launch_bounds__(1024)
void gen_tables(float* __restrict__ Tc, float* __restrict__ Ts, float* __restrict__ w)
{
    const int tid = threadIdx.x;
    const float step = 6.28318530717958647692f / 64.0f;
    for (int i = tid; i < 4096; i += 1024) {
        int p = i >> 6, q = i & 63;
        float ang = (float)((p * q) & 63) * step;
        Tc[i] = cosf(ang);
        Ts[i] = sinf(ang);
    }
    // w[j] = h^{-alpha} * cumprod_{i=1..j} ((i-1.5)/i) via chunked wave scan
    if (tid < 64) {
        const int l = tid;
        float vals[16];
        float local = 1.0f;
        #pragma unroll
        for (int m = 0; m < 16; ++m) {
            int j = 16 * l + 1 + m;
            local *= ((float)j - 1.5f) / (float)j;
            vals[m] = local;
        }
        float scan = local;
        #pragma unroll
        for (int d = 1; d < 64; d <<= 1) {
            float o = __shfl_up(scan, (unsigned)d, 64);
            if (l >= d) scan *= o;
        }
        float prefix = __shfl_up(scan, 1u, 64);
        if (l == 0) prefix = 1.0f;
        const float s = sqrtf((float)(NTOT - 1));
        if (l == 0) w[0] = s;
        #pragma unroll
        for (int m = 0; m < 16; ++m) {
            int j = 16 * l + 1 + m;
            if (j < CTAPS) w[j] = prefix * vals[m] * s;
        }
    }
}

// ---------------------------------------------------------- fused 2-D DFT ---
// One block per 64x64 image (same validated math as round 2).
__global__ __launch_bounds__(256)
void dft2_real(const float* __restrict__ X, const float* __restrict__ Tc,
               const float* __restrict__ Ts, float* __restrict__ out, float scale)
{
    __shared__ float Xs[64 * 65];
    __shared__ __align__(16) float Cs[64][68];
    __shared__ __align__(16) float Ss[64][68];
    const int tid = threadIdx.x;
    const int img = blockIdx.x;

    const float4* X4 = (const float4*)(X + (size_t)img * 4096);
    #pragma unroll
    for (int i = 0; i < 4; ++i) {
        int li = tid + i * 256;
        int r = li >> 4, m0 = (li & 15) * 4;
        float4 v = X4[li];
        float* p = &Xs[r * 65 + m0];
        p[0] = v.x; p[1] = v.y; p[2] = v.z; p[3] = v.w;
    }
    __syncthreads();

    const int tx = tid & 15, ty = tid >> 4;
    const int p0 = ty * 4, q0 = tx * 4;

    float c[4][4] = {}, s[4][4] = {};
    for (int m = 0; m < 64; ++m) {
        float4 tcv = *(const float4*)&Tc[m * 64 + q0];
        float4 tsv = *(const float4*)&Ts[m * 64 + q0];
        float tc_[4] = {tcv.x, tcv.y, tcv.z, tcv.w};
        float ts_[4] = {tsv.x, tsv.y, tsv.z, tsv.w};
        float a_[4];
        #pragma unroll
        for (int i = 0; i < 4; ++i) a_[i] = Xs[(p0 + i) * 65 + m];
        #pragma unroll
        for (int i = 0; i < 4; ++i)
            #pragma unroll
            for (int j = 0; j < 4; ++j) {
                c[i][j] = fmaf(a_[i], tc_[j], c[i][j]);
                s[i][j] = fmaf(a_[i], ts_[j], s[i][j]);
            }
    }
    #pragma unroll
    for (int i = 0; i < 4; ++i) {
        float4 cv = {c[i][0], c[i][1], c[i][2], c[i][3]};
        float4 sv = {s[i][0], s[i][1], s[i][2], s[i][3]};
        *(float4*)&Cs[p0 + i][q0] = cv;
        *(float4*)&Ss[p0 + i][q0] = sv;
    }
    __syncthreads();

    float acc[4][4] = {};
    for (int m = 0; m < 64; ++m) {
        float4 tcv = *(const float4*)&Tc[m * 64 + p0];
        float4 tsv = *(const float4*)&Ts[m * 64 + p0];
        float4 cv  = *(const float4*)&Cs[m][q0];
        float4 sv  = *(const float4*)&Ss[m][q0];
        float tc_[4] = {tcv.x, tcv.y, tcv.z, tcv.w};
        float ts_[4] = {tsv.x, tsv.y, tsv.z, tsv.w};
        float c_[4]  = {cv.x, cv.y, cv.z, cv.w};
        float s_[4]  = {sv.x, sv.y, sv.z, sv.w};
        #pragma unroll
        for (int i = 0; i < 4; ++i)
            #pragma unroll
            for (int j = 0; j < 4; ++j)
                acc[i][j] += tc_[i] * c_[j] - ts_[i] * s_[j];
    }
    float* o = out + (size_t)img * 4096;
    #pragma unroll
    for (int i = 0; i < 4; ++i) {
        float4 v = {acc[i][0] * scale, acc[i][1] * scale,
                    acc[i][2] * scale, acc[i][3] * scale};
        *(float4*)&o[(p0 + i) * 64 + q0] = v;
    }
}

// ---------------------------------------------------------------- conv ------
// fr[k] = sum_{j<1024} w[j]*f[k-j]; writes bf16 (feeds the MFMA stack).
__global__ __launch_bounds__(256)
void conv_gl(const float* __restrict__ f, const float* __restrict__ w,
             unsigned short* __restrict__ fr)
{
    __shared__ __align__(16) float fs[COUT + CTAPS + 8];
    const int tid = threadIdx.x;
    const long long k0 = (long long)blockIdx.x * COUT;
    const long long base = k0 - (CTAPS + 8);
    for (int i = tid; i < COUT + CTAPS + 8; i += 256) {
        long long g = base + i;
        fs[i] = (g >= 0) ? f[g] : 0.0f;
    }
    __syncthreads();
    const int sl = tid * 8 + CTAPS + 8;
    float acc[8] = {0, 0, 0, 0, 0, 0, 0, 0};
    float win[16];
    #pragma unroll
    for (int i = 0; i < 16; ++i) win[i] = fs[sl - 8 + i];
    for (int j0 = 0; j0 < CTAPS; j0 += 8) {
        float wv[8];
        #pragma unroll
        for (int jj = 0; jj < 8; ++jj) wv[jj] = w[j0 + jj];
        #pragma unroll
        for (int jj = 0; jj < 8; ++jj)
            #pragma unroll
            for (int o = 0; o < 8; ++o)
                acc[o] = fmaf(wv[jj], win[8 + o - jj], acc[o]);
        if (j0 + 8 < CTAPS) {
            float nw[8];
            #pragma unroll
            for (int i = 0; i < 8; ++i) nw[i] = fs[sl - j0 - 16 + i];
            #pragma unroll
            for (int i = 0; i < 8; ++i) win[8 + i] = win[i];
            #pragma unroll
            for (int i = 0; i < 8; ++i) win[i] = nw[i];
        }
    }
    u16x8 v;
    #pragma unroll
    for (int i = 0; i < 8; ++i) v[i] = f2bf(acc[i]);
    *(u16x8*)&fr[k0 + tid * 8] = v;
}

// ------------------------------------------------------------- MFMA GEMM ----
// D = A(bf16, MxK row-major) @ W(f32, KxN row-major, converted inline).
// 128x128 tile, 4 waves (2x2 of 64x64), BK=32, mfma_f32_16x16x32_bf16.
// A-fragments straight from global (A is tiny & L2-resident); W staged to LDS
// transposed [n][k] pad-40 (80B stride -> 2-way bank alias = free), b128 reads.
// MODE 0: f32 partial at Out + z*M*N.  MODE 1: f32 final (+bias).  MODE 2: bf16 final (+bias).
template<int MODE, int RELU>
__global__ __launch_bounds__(256)
void mfma_gemm(const unsigned short* __restrict__ A, const float* __restrict__ W,
               void* __restrict__ Out, const float* __restrict__ bias,
               int M, int N, int K, int kChunk)
{
    __shared__ unsigned short Bs[128 * 40];
    const int tid = threadIdx.x;
    const int bm = blockIdx.x * 128;
    const int bn = blockIdx.y * 128;
    const int z  = blockIdx.z;
    const int kb0 = z * kChunk;
    const int nsteps = kChunk >> 5;

    const int lane = tid & 63;
    const int wv = tid >> 6;
    const int wr = (wv >> 1) * 64, wc = (wv & 1) * 64;
    const int l15 = lane & 15, l4 = lane >> 4;

    const int sn  = (tid & 63) * 2;     // staged n-pair
    const int sk8 = (tid >> 6) * 8;     // staged k-octet

    f32x4 acc[4][4];
    #pragma unroll
    for (int i = 0; i < 4; ++i)
        #pragma unroll
        for (int j = 0; j < 4; ++j)
            acc[i][j] = (f32x4){0.f, 0.f, 0.f, 0.f};

    float2 breg[8];
    auto loadB = [&](int kb) {
        const float* Wp = W + (size_t)(kb + sk8) * N + bn + sn;
        #pragma unroll
        for (int e = 0; e < 8; ++e)
            breg[e] = *(const float2*)(Wp + (size_t)e * N);
    };
    auto writeB = [&]() {
        u16x8 p0, p1;
        #pragma unroll
        for (int e = 0; e < 8; ++e) { p0[e] = f2bf(breg[e].x); p1[e] = f2bf(breg[e].y); }
        *(u16x8*)&Bs[sn * 40 + sk8]       = p0;
        *(u16x8*)&Bs[(sn + 1) * 40 + sk8] = p1;
    };

    loadB(kb0);
    writeB();
    __syncthreads();

    for (int step = 0; step < nsteps; ++step) {
        const int kb = kb0 + step * 32;
        bf16x8 fa[4], fb[4];
        const unsigned short* Ap = A + (size_t)(bm + wr + l15) * K + kb + l4 * 8;
        #pragma unroll
        for (int m4 = 0; m4 < 4; ++m4)
            fa[m4] = *(const bf16x8*)(Ap + (size_t)m4 * 16 * K);
        if (step + 1 < nsteps) loadB(kb + 32);
        #pragma unroll
        for (int n4 = 0; n4 < 4; ++n4)
            fb[n4] = *(const bf16x8*)&Bs[(wc + n4 * 16 + l15) * 40 + l4 * 8];
        #pragma unroll
        for (int m4 = 0; m4 < 4; ++m4)
            #pragma unroll
            for (int n4 = 0; n4 < 4; ++n4)
                acc[m4][n4] = __builtin_amdgcn_mfma_f32_16x16x32_bf16(
                    fa[m4], fb[n4], acc[m4][n4], 0, 0, 0);
        __syncthreads();
        if (step + 1 < nsteps) { writeB(); }
        __syncthreads();
    }

    // epilogue: C/D layout col=lane&15, row=(lane>>4)*4+reg  [m89-verified]
    #pragma unroll
    for (int m4 = 0; m4 < 4; ++m4)
        #pragma unroll
        for (int n4 = 0; n4 < 4; ++n4) {
            const int col = bn + wc + n4 * 16 + l15;
            const int row0 = bm + wr + m4 * 16 + l4 * 4;
            #pragma unroll
            for (int r = 0; r < 4; ++r) {
                float v = acc[m4][n4][r];
                if (MODE == 0) {
                    ((float*)Out)[(size_t)z * M * N + (size_t)(row0 + r) * N + col] = v;
                } else {
                    v += bias[col];
                    if (RELU) v = fmaxf(v, 0.f);
                    if (MODE == 1)
                        ((float*)Out)[(size_t)(row0 + r) * N + col] = v;
                    else
                        ((unsigned short*)Out)[(size_t)(row0 + r) * N + col] = f2bf(v);
                }
            }
        }
}

// --------------------------------------------------------------- reduce -----
template<int RELU, int OUTBF>
__global__ __launch_bounds__(256)
void reduce_bias(const float* __restrict__ P, const float* __restrict__ bias,
                 void* __restrict__ C, int MN, int N, int S)
{
    const int idx4 = blockIdx.x * 256 + threadIdx.x;
    const int MN4 = MN >> 2;
    if (idx4 >= MN4) return;
    const float4* P4 = (const float4*)P;
    float4 a = P4[idx4];
    for (int zz = 1; zz < S; ++zz) {
        float4 b = P4[(size_t)zz * MN4 + idx4];
        a.x += b.x; a.y += b.y; a.z += b.z; a.w += b.w;
    }
    int n0 = (idx4 * 4) % N;
    a.x += bias[n0]; a.y += bias[n0 + 1]; a.z += bias[n0 + 2]; a.w += bias[n0 + 3];
    if (RELU) {
        a.x = fmaxf(a.x, 0.f); a.y = fmaxf(a.y, 0.f);
        a.z = fmaxf(a.z, 0.f); a.w = fmaxf(a.w, 0.f);
    }
    if (OUTBF) {
        ushort4 v = {f2bf(a.x), f2bf(a.y), f2bf(a.z), f2bf(a.w)};
        ((ushort4*)C)[idx4] = v;
    } else {
        ((float4*)C)[idx4] = a;
    }
}

// ---------------------------------------------------------------- launch ----
extern "C" void kernel_launch(void* const* d_in, const int* in_sizes, int n_in,
                              void* d_out, int out_size, void* d_ws, size_t ws_size,
                              hipStream_t stream)
{
    const float* x   = (const float*)d_in[0];
    const float* Ws1 = (const float*)d_in[1];
    const float* bs1 = (const float*)d_in[2];
    const float* Ws2 = (const float*)d_in[3];
    const float* bs2 = (const float*)d_in[4];
    const float* Wn1 = (const float*)d_in[5];
    const float* bn1 = (const float*)d_in[6];
    const float* Wn2 = (const float*)d_in[7];
    const float* bn2 = (const float*)d_in[8];
    const float* Wn3 = (const float*)d_in[9];
    const float* bn3 = (const float*)d_in[10];
    float* out = (float*)d_out;

    char* wsb = (char*)d_ws;
    float* Tc  = (float*)wsb; wsb += 16384;
    float* Ts  = (float*)wsb; wsb += 16384;
    float* wgl = (float*)wsb; wsb += 4096;
    unsigned short* fr   = (unsigned short*)wsb; wsb += (size_t)NTOT * 2;
    unsigned short* spec = (unsigned short*)wsb; wsb += (size_t)NTOT * 2;
    unsigned short* t1   = (unsigned short*)wsb; wsb += 262144;
    unsigned short* h1   = (unsigned short*)wsb; wsb += 262144;
    unsigned short* h2   = (unsigned short*)wsb; wsb += 262144;
    float* part = (float*)wsb; wsb += (size_t)32 * 131072 * 4;
    float* bufA = (float*)wsb; wsb += (size_t)NTOT * 4;

    gen_tables<<<1, 1024, 0, stream>>>(Tc, Ts, wgl);

    // forward fft2 real part (fused row+col DFT)
    dft2_real<<<NIMG, 256, 0, stream>>>(x, Tc, Ts, bufA, 1.0f);

    // GL fractional conv -> fr (bf16)
    conv_gl<<<NTOT / COUT, 256, 0, stream>>>(bufA, wgl, fr);

    // spectral_operator
    mfma_gemm<0, 0><<<dim3(2, 4, 32), 256, 0, stream>>>(fr, Ws1, part, nullptr,
                                                        256, 512, 12288, 384);
    reduce_bias<1, 1><<<128, 256, 0, stream>>>(part, bs1, t1, 131072, 512, 32);
    mfma_gemm<2, 0><<<dim3(2, 96, 1), 256, 0, stream>>>(t1, Ws2, spec, bs2,
                                                        256, 12288, 512, 512);

    // neural_operator
    mfma_gemm<0, 0><<<dim3(2, 4, 32), 256, 0, stream>>>(spec, Wn1, part, nullptr,
                                                        256, 512, 12288, 384);
    reduce_bias<1, 1><<<128, 256, 0, stream>>>(part, bn1, h1, 131072, 512, 32);
    mfma_gemm<0, 0><<<dim3(2, 4, 8), 256, 0, stream>>>(h1, Wn2, part, nullptr,
                                                       256, 512, 512, 64);
    reduce_bias<1, 1><<<128, 256, 0, stream>>>(part, bn2, h2, 131072, 512, 8);
    mfma_gemm<1, 0><<<dim3(2, 96, 1), 256, 0, stream>>>(h2, Wn3, bufA, bn3,
                                                        256, 12288, 512, 512);

    // inverse fft2 real part
    dft2_real<<<NIMG, 256, 0, stream>>>(bufA, Tc, Ts, out, 1.0f / 4096.0f);
}

// Round 5
// 203.021 us; speedup vs baseline: 2.7601x; 1.2822x over previous
//
#include <hip/hip_runtime.h>
#include <hip/hip_bf16.h>

#define NTOT 3145728   // 256*3*64*64
#define NIMG 768       // 256*3
#define CTAPS 1024     // GL conv truncation
#define NBAND 66       // conv bands: d = -1 .. 64

typedef __attribute__((ext_vector_type(8)))  short bf16x8;
typedef __attribute__((ext_vector_type(4)))  short bf16x4;
typedef __attribute__((ext_vector_type(8)))  unsigned short u16x8;
typedef __attribute__((ext_vector_type(4)))  float f32x4;
typedef __attribute__((ext_vector_type(16))) float f32x16;

__device__ inline unsigned short f2bf(float x) {
    unsigned u = __builtin_bit_cast(unsigned, x);
    u += 0x7fffu + ((u >> 16) & 1u);
    return (unsigned short)(u >> 16);
}
__device__ inline float bf2f(unsigned short u) {
    return __builtin_bit_cast(float, (unsigned)u << 16);
}
__device__ inline void split2(float v, unsigned short& hi, unsigned short& lo) {
    hi = f2bf(v);
    lo = f2bf(v - bf2f(hi));
}
__device__ inline bf16x8 ld2(const unsigned short* p) {   // 8B-aligned LDS read
    bf16x4 a = *(const bf16x4*)p;
    bf16x4 b = *(const bf16x4*)(p + 4);
    bf16x8 r;
    #pragma unroll
    for (int i = 0; i < 4; ++i) { r[i] = a[i]; r[4 + i] = b[i]; }
    return r;
}

// ---------------------------------------------------------------- tables ----
// hi/lo bf16 DFT tables, hi/lo GL band matrices Bt[d+1][o][u] = w[16d+o-u],
// and zero prefixes for the hi/lo f buffers.
__global__ __launch_bounds__(1024)
void gen_tables(unsigned short* __restrict__ Tch, unsigned short* __restrict__ Tcl,
                unsigned short* __restrict__ Tsh, unsigned short* __restrict__ Tsl,
                unsigned short* __restrict__ Bth, unsigned short* __restrict__ Btl,
                unsigned short* __restrict__ fph, unsigned short* __restrict__ fpl)
{
    __shared__ float wsm[CTAPS];
    const int tid = threadIdx.x;
    const float step = 6.28318530717958647692f / 64.0f;
    for (int i = tid; i < 4096; i += 1024) {
        int p = i >> 6, q = i & 63;
        float ang = (float)((p * q) & 63) * step;
        unsigned short h, l;
        split2(cosf(ang), h, l); Tch[i] = h; Tcl[i] = l;
        split2(sinf(ang), h, l); Tsh[i] = h; Tsl[i] = l;
    }
    fph[tid] = 0; fpl[tid] = 0;   // 1024-element zero prefixes
    // w[j] = h^{-alpha} * cumprod_{i=1..j} ((i-1.5)/i) via chunked wave scan
    if (tid < 64) {
        const int l = tid;
        float vals[16];
        float local = 1.0f;
        #pragma unroll
        for (int m = 0; m < 16; ++m) {
            int j = 16 * l + 1 + m;
            local *= ((float)j - 1.5f) / (float)j;
            vals[m] = local;
        }
        float scan = local;
        #pragma unroll
        for (int d = 1; d < 64; d <<= 1) {
            float o = __shfl_up(scan, (unsigned)d, 64);
            if (l >= d) scan *= o;
        }
        float prefix = __shfl_up(scan, 1u, 64);
        if (l == 0) prefix = 1.0f;
        const float s = sqrtf((float)(NTOT - 1));
        if (l == 0) wsm[0] = s;
        #pragma unroll
        for (int m = 0; m < 16; ++m) {
            int j = 16 * l + 1 + m;
            if (j < CTAPS) wsm[j] = prefix * vals[m] * s;
        }
    }
    __syncthreads();
    for (int i = tid; i < NBAND * 512; i += 1024) {
        int d = (i >> 9) - 1, o = (i >> 4) & 31, u = i & 15;
        int j = 16 * d + o - u;
        unsigned short h = 0, l = 0;
        if (j >= 0 && j < CTAPS) split2(wsm[j], h, l);
        Bth[i] = h; Btl[i] = l;
    }
}

// ---------------------------------------------------------- MFMA 2-D DFT ---
// One block per 64x64 image, 4 waves (one 32x32 quadrant each). hi/lo split
// operands, 3 accumulation chains (drops only lo*lo ~2^-18).
// Row pass (operand-swapped): Ct = Tc * X^T ; St stores -(Ts * X^T).
// Col pass: out = Tc*Ct + Ts*St.
template<int INV>
__global__ __launch_bounds__(256)
void dft_mfma(const void* __restrict__ Xin, const unsigned short* __restrict__ Xlo_in,
              const unsigned short* __restrict__ Tch, const unsigned short* __restrict__ Tcl,
              const unsigned short* __restrict__ Tsh, const unsigned short* __restrict__ Tsl,
              void* __restrict__ Out, unsigned short* __restrict__ Out2)
{
    __shared__ __align__(16) unsigned short Xh[64 * 68], Xl[64 * 68];
    __shared__ __align__(16) unsigned short Chh[64 * 68], Cll[64 * 68];
    __shared__ __align__(16) unsigned short Shh[64 * 68], Sll[64 * 68];
    const int tid = threadIdx.x;
    const int img = blockIdx.x;
    {
        const int rr = tid >> 2, c0 = (tid & 3) * 16;
        const int lb = rr * 68 + c0;
        if (!INV) {
            const float* Xf = (const float*)Xin + (size_t)img * 4096 + rr * 64 + c0;
            #pragma unroll
            for (int i = 0; i < 4; ++i) {
                float4 v = *(const float4*)(Xf + 4 * i);
                float vv[4] = {v.x, v.y, v.z, v.w};
                #pragma unroll
                for (int k = 0; k < 4; ++k) {
                    unsigned short h, l; split2(vv[k], h, l);
                    Xh[lb + 4 * i + k] = h; Xl[lb + 4 * i + k] = l;
                }
            }
        } else {
            const unsigned short* Ph = (const unsigned short*)Xin + (size_t)img * 4096 + rr * 64 + c0;
            const unsigned short* Pl = Xlo_in + (size_t)img * 4096 + rr * 64 + c0;
            #pragma unroll
            for (int i = 0; i < 4; ++i) {
                *(ushort4*)&Xh[lb + 4 * i] = *(const ushort4*)(Ph + 4 * i);
                *(ushort4*)&Xl[lb + 4 * i] = *(const ushort4*)(Pl + 4 * i);
            }
        }
    }
    __syncthreads();

    const int lane = tid & 63, wv = tid >> 6;
    const int r = lane & 31, g = lane >> 5;
    const int q0 = (wv >> 1) * 32, r0 = (wv & 1) * 32;
    const int tA = (q0 + r) * 64;     // T row base (A operand)
    const int xB = (r0 + r) * 68;     // X / C / S row base (B operand)

    f32x16 a1, a2, a3;
    // ---- row pass, cos
    #pragma unroll
    for (int i = 0; i < 16; ++i) { a1[i] = 0.f; a2[i] = 0.f; a3[i] = 0.f; }
    #pragma unroll
    for (int ks = 0; ks < 4; ++ks) {
        const int ko = ks * 16 + 8 * g;
        bf16x8 xh = ld2(&Xh[xB + ko]);
        bf16x8 xl = ld2(&Xl[xB + ko]);
        bf16x8 th = *(const bf16x8*)&Tch[tA + ko];
        bf16x8 tl = *(const bf16x8*)&Tcl[tA + ko];
        a1 = __builtin_amdgcn_mfma_f32_32x32x16_bf16(th, xh, a1, 0, 0, 0);
        a2 = __builtin_amdgcn_mfma_f32_32x32x16_bf16(th, xl, a2, 0, 0, 0);
        a3 = __builtin_amdgcn_mfma_f32_32x32x16_bf16(tl, xh, a3, 0, 0, 0);
    }
    #pragma unroll
    for (int reg = 0; reg < 16; ++reg) {
        int qq = q0 + (reg & 3) + 8 * (reg >> 2) + 4 * g;
        unsigned short h, l; split2(a1[reg] + a2[reg] + a3[reg], h, l);
        Chh[qq * 68 + r0 + r] = h; Cll[qq * 68 + r0 + r] = l;
    }
    // ---- row pass, sin (stored negated)
    #pragma unroll
    for (int i = 0; i < 16; ++i) { a1[i] = 0.f; a2[i] = 0.f; a3[i] = 0.f; }
    #pragma unroll
    for (int ks = 0; ks < 4; ++ks) {
        const int ko = ks * 16 + 8 * g;
        bf16x8 xh = ld2(&Xh[xB + ko]);
        bf16x8 xl = ld2(&Xl[xB + ko]);
        bf16x8 th = *(const bf16x8*)&Tsh[tA + ko];
        bf16x8 tl = *(const bf16x8*)&Tsl[tA + ko];
        a1 = __builtin_amdgcn_mfma_f32_32x32x16_bf16(th, xh, a1, 0, 0, 0);
        a2 = __builtin_amdgcn_mfma_f32_32x32x16_bf16(th, xl, a2, 0, 0, 0);
        a3 = __builtin_amdgcn_mfma_f32_32x32x16_bf16(tl, xh, a3, 0, 0, 0);
    }
    #pragma unroll
    for (int reg = 0; reg < 16; ++reg) {
        int qq = q0 + (reg & 3) + 8 * (reg >> 2) + 4 * g;
        unsigned short h, l; split2(-(a1[reg] + a2[reg] + a3[reg]), h, l);
        Shh[qq * 68 + r0 + r] = h; Sll[qq * 68 + r0 + r] = l;
    }
    __syncthreads();

    // ---- col pass
    #pragma unroll
    for (int i = 0; i < 16; ++i) { a1[i] = 0.f; a2[i] = 0.f; a3[i] = 0.f; }
    #pragma unroll
    for (int ks = 0; ks < 4; ++ks) {
        const int ko = ks * 16 + 8 * g;
        bf16x8 ch = ld2(&Chh[xB + ko]);
        bf16x8 cl = ld2(&Cll[xB + ko]);
        bf16x8 th = *(const bf16x8*)&Tch[tA + ko];
        bf16x8 tl = *(const bf16x8*)&Tcl[tA + ko];
        a1 = __builtin_amdgcn_mfma_f32_32x32x16_bf16(th, ch, a1, 0, 0, 0);
        a2 = __builtin_amdgcn_mfma_f32_32x32x16_bf16(th, cl, a2, 0, 0, 0);
        a3 = __builtin_amdgcn_mfma_f32_32x32x16_bf16(tl, ch, a3, 0, 0, 0);
        bf16x8 sh = ld2(&Shh[xB + ko]);
        bf16x8 sl = ld2(&Sll[xB + ko]);
        bf16x8 uh = *(const bf16x8*)&Tsh[tA + ko];
        bf16x8 ul = *(const bf16x8*)&Tsl[tA + ko];
        a1 = __builtin_amdgcn_mfma_f32_32x32x16_bf16(uh, sh, a1, 0, 0, 0);
        a2 = __builtin_amdgcn_mfma_f32_32x32x16_bf16(uh, sl, a2, 0, 0, 0);
        a3 = __builtin_amdgcn_mfma_f32_32x32x16_bf16(ul, sh, a3, 0, 0, 0);
    }
    #pragma unroll
    for (int reg = 0; reg < 16; ++reg) {
        int pp = q0 + (reg & 3) + 8 * (reg >> 2) + 4 * g;
        float v = a1[reg] + a2[reg] + a3[reg];
        size_t oi = (size_t)img * 4096 + (size_t)pp * 64 + r0 + r;
        if (INV) {
            ((float*)Out)[oi] = v * (1.0f / 4096.0f);
        } else {
            unsigned short h, l; split2(v, h, l);
            ((unsigned short*)Out)[oi] = h; Out2[oi] = l;
        }
    }
}

// ----------------------------------------------------------- MFMA conv -----
// GL conv as banded block-GEMM with d = -1..64 (66 bands):
//   out[s][o] = sum_d A_d @ B_d,  A_d[s][v] = f[tb + 32s - 16d + v],
//   B_d[v][o] = w[16d + o - v] (masked to 0 <= j < 1024).
// Coverage per o: j in [o-31, o+1024] intersect [0,1023] -- complete, unique.
// hi/lo split f and w, 3 chains; 198 mfma_32x32x16 per wave (1024 outputs).
__global__ __launch_bounds__(256)
void conv_mfma(const unsigned short* __restrict__ fh, const unsigned short* __restrict__ fl,
               const unsigned short* __restrict__ Bth, const unsigned short* __restrict__ Btl,
               unsigned short* __restrict__ fr)
{
    const int tid = threadIdx.x;
    const int lane = tid & 63;
    const int wv = tid >> 6;
    const int r = lane & 31, g = lane >> 5;
    const size_t tb = ((size_t)blockIdx.x * 4 + wv) * 1024;
    const unsigned short* fah = fh + tb + 32 * r + 8 * g + 16;   // dd=0 is d=-1
    const unsigned short* fal = fl + tb + 32 * r + 8 * g + 16;
    const int bo = 16 * r + 8 * g;
    f32x16 a1, a2, a3;
    #pragma unroll
    for (int i = 0; i < 16; ++i) { a1[i] = 0.f; a2[i] = 0.f; a3[i] = 0.f; }
    for (int dd = 0; dd < NBAND; ++dd) {
        bf16x8 avh = *(const bf16x8*)(fah - 16 * dd);
        bf16x8 avl = *(const bf16x8*)(fal - 16 * dd);
        bf16x8 bvh = *(const bf16x8*)(Bth + 512 * dd + bo);
        bf16x8 bvl = *(const bf16x8*)(Btl + 512 * dd + bo);
        a1 = __builtin_amdgcn_mfma_f32_32x32x16_bf16(avh, bvh, a1, 0, 0, 0);
        a2 = __builtin_amdgcn_mfma_f32_32x32x16_bf16(avl, bvh, a2, 0, 0, 0);
        a3 = __builtin_amdgcn_mfma_f32_32x32x16_bf16(avh, bvl, a3, 0, 0, 0);
    }
    #pragma unroll
    for (int reg = 0; reg < 16; ++reg) {
        int row = (reg & 3) + 8 * (reg >> 2) + 4 * g;
        fr[tb + 32 * row + r] = f2bf(a1[reg] + a2[reg] + a3[reg]);
    }
}

// ------------------------------------------------------------- MFMA GEMM ----
// D = A(bf16, MxK row-major) @ W(f32, KxN row-major, converted inline).
// 128x128 tile, 4 waves, BK=32, mfma_f32_16x16x32_bf16 (validated round 3).
// MODE 0: f32 partial at Out + z*M*N.  MODE 1: f32 final (+bias).
// MODE 2: bf16 final (+bias).  MODE 3: bf16 hi/lo pair final (+bias).
template<int MODE, int RELU>
__global__ __launch_bounds__(256)
void mfma_gemm(const unsigned short* __restrict__ A, const float* __restrict__ W,
               void* __restrict__ Out, const float* __restrict__ bias,
               int M, int N, int K, int kChunk, unsigned short* __restrict__ Out2)
{
    __shared__ unsigned short Bs[128 * 40];
    const int tid = threadIdx.x;
    const int bm = blockIdx.x * 128;
    const int bn = blockIdx.y * 128;
    const int z  = blockIdx.z;
    const int kb0 = z * kChunk;
    const int nsteps = kChunk >> 5;

    const int lane = tid & 63;
    const int wv = tid >> 6;
    const int wr = (wv >> 1) * 64, wc = (wv & 1) * 64;
    const int l15 = lane & 15, l4 = lane >> 4;

    const int sn  = (tid & 63) * 2;
    const int sk8 = (tid >> 6) * 8;

    f32x4 acc[4][4];
    #pragma unroll
    for (int i = 0; i < 4; ++i)
        #pragma unroll
        for (int j = 0; j < 4; ++j)
            acc[i][j] = (f32x4){0.f, 0.f, 0.f, 0.f};

    float2 breg[8];
    auto loadB = [&](int kb) {
        const float* Wp = W + (size_t)(kb + sk8) * N + bn + sn;
        #pragma unroll
        for (int e = 0; e < 8; ++e)
            breg[e] = *(const float2*)(Wp + (size_t)e * N);
    };
    auto writeB = [&]() {
        u16x8 p0, p1;
        #pragma unroll
        for (int e = 0; e < 8; ++e) { p0[e] = f2bf(breg[e].x); p1[e] = f2bf(breg[e].y); }
        *(u16x8*)&Bs[sn * 40 + sk8]       = p0;
        *(u16x8*)&Bs[(sn + 1) * 40 + sk8] = p1;
    };

    loadB(kb0);
    writeB();
    __syncthreads();

    for (int step = 0; step < nsteps; ++step) {
        const int kb = kb0 + step * 32;
        bf16x8 fa[4], fb2[4];
        const unsigned short* Ap = A + (size_t)(bm + wr + l15) * K + kb + l4 * 8;
        #pragma unroll
        for (int m4 = 0; m4 < 4; ++m4)
            fa[m4] = *(const bf16x8*)(Ap + (size_t)m4 * 16 * K);
        if (step + 1 < nsteps) loadB(kb + 32);
        #pragma unroll
        for (int n4 = 0; n4 < 4; ++n4)
            fb2[n4] = *(const bf16x8*)&Bs[(wc + n4 * 16 + l15) * 40 + l4 * 8];
        #pragma unroll
        for (int m4 = 0; m4 < 4; ++m4)
            #pragma unroll
            for (int n4 = 0; n4 < 4; ++n4)
                acc[m4][n4] = __builtin_amdgcn_mfma_f32_16x16x32_bf16(
                    fa[m4], fb2[n4], acc[m4][n4], 0, 0, 0);
        __syncthreads();
        if (step + 1 < nsteps) { writeB(); }
        __syncthreads();
    }

    #pragma unroll
    for (int m4 = 0; m4 < 4; ++m4)
        #pragma unroll
        for (int n4 = 0; n4 < 4; ++n4) {
            const int col = bn + wc + n4 * 16 + l15;
            const int row0 = bm + wr + m4 * 16 + l4 * 4;
            #pragma unroll
            for (int rg = 0; rg < 4; ++rg) {
                float v = acc[m4][n4][rg];
                const size_t oi = (size_t)(row0 + rg) * N + col;
                if (MODE == 0) {
                    ((float*)Out)[(size_t)z * M * N + oi] = v;
                } else {
                    v += bias[col];
                    if (RELU) v = fmaxf(v, 0.f);
                    if (MODE == 1) {
                        ((float*)Out)[oi] = v;
                    } else if (MODE == 2) {
                        ((unsigned short*)Out)[oi] = f2bf(v);
                    } else {
                        unsigned short h, l; split2(v, h, l);
                        ((unsigned short*)Out)[oi] = h; Out2[oi] = l;
                    }
                }
            }
        }
}

// --------------------------------------------------------------- reduce -----
template<int RELU, int OUTBF>
__global__ __launch_bounds__(256)
void reduce_bias(const float* __restrict__ P, const float* __restrict__ bias,
                 void* __restrict__ C, int MN, int N, int S)
{
    const int idx4 = blockIdx.x * 256 + threadIdx.x;
    const int MN4 = MN >> 2;
    if (idx4 >= MN4) return;
    const float4* P4 = (const float4*)P;
    float4 a = P4[idx4];
    for (int zz = 1; zz < S; ++zz) {
        float4 b = P4[(size_t)zz * MN4 + idx4];
        a.x += b.x; a.y += b.y; a.z += b.z; a.w += b.w;
    }
    int n0 = (idx4 * 4) % N;
    a.x += bias[n0]; a.y += bias[n0 + 1]; a.z += bias[n0 + 2]; a.w += bias[n0 + 3];
    if (RELU) {
        a.x = fmaxf(a.x, 0.f); a.y = fmaxf(a.y, 0.f);
        a.z = fmaxf(a.z, 0.f); a.w = fmaxf(a.w, 0.f);
    }
    if (OUTBF) {
        ushort4 v = {f2bf(a.x), f2bf(a.y), f2bf(a.z), f2bf(a.w)};
        ((ushort4*)C)[idx4] = v;
    } else {
        ((float4*)C)[idx4] = a;
    }
}

// ---------------------------------------------------------------- launch ----
extern "C" void kernel_launch(void* const* d_in, const int* in_sizes, int n_in,
                              void* d_out, int out_size, void* d_ws, size_t ws_size,
                              hipStream_t stream)
{
    const float* x   = (const float*)d_in[0];
    const float* Ws1 = (const float*)d_in[1];
    const float* bs1 = (const float*)d_in[2];
    const float* Ws2 = (const float*)d_in[3];
    const float* bs2 = (const float*)d_in[4];
    const float* Wn1 = (const float*)d_in[5];
    const float* bn1 = (const float*)d_in[6];
    const float* Wn2 = (const float*)d_in[7];
    const float* bn2 = (const float*)d_in[8];
    const float* Wn3 = (const float*)d_in[9];
    const float* bn3 = (const float*)d_in[10];
    float* out = (float*)d_out;

    char* p = (char*)d_ws;
    auto alloc = [&](size_t bytes) { char* q = p; p += (bytes + 255) & ~(size_t)255; return q; };
    unsigned short* Tch = (unsigned short*)alloc(8192);
    unsigned short* Tcl = (unsigned short*)alloc(8192);
    unsigned short* Tsh = (unsigned short*)alloc(8192);
    unsigned short* Tsl = (unsigned short*)alloc(8192);
    unsigned short* Bth = (unsigned short*)alloc((size_t)NBAND * 512 * 2);
    unsigned short* Btl = (unsigned short*)alloc((size_t)NBAND * 512 * 2);
    unsigned short* fhb = (unsigned short*)alloc((size_t)(1024 + NTOT) * 2);
    unsigned short* flb = (unsigned short*)alloc((size_t)(1024 + NTOT) * 2);
    unsigned short* fr   = (unsigned short*)alloc((size_t)NTOT * 2);
    unsigned short* spec = (unsigned short*)alloc((size_t)NTOT * 2);
    unsigned short* ph   = (unsigned short*)alloc((size_t)NTOT * 2);
    unsigned short* pl   = (unsigned short*)alloc((size_t)NTOT * 2);
    unsigned short* t1   = (unsigned short*)alloc(262144);
    unsigned short* h1   = (unsigned short*)alloc(262144);
    unsigned short* h2   = (unsigned short*)alloc(262144);
    float* part          = (float*)alloc((size_t)32 * 131072 * 4);

    gen_tables<<<1, 1024, 0, stream>>>(Tch, Tcl, Tsh, Tsl, Bth, Btl, fhb, flb);

    // forward fft2 real part -> hi/lo bf16 f (offset 1024, zero prefix)
    dft_mfma<0><<<NIMG, 256, 0, stream>>>(x, nullptr, Tch, Tcl, Tsh, Tsl,
                                          fhb + 1024, flb + 1024);

    // GL fractional conv (banded block-GEMM, 66 bands, hi/lo) -> fr (bf16)
    conv_mfma<<<NTOT / 4096, 256, 0, stream>>>(fhb + 1024, flb + 1024, Bth, Btl, fr);

    // spectral_operator
    mfma_gemm<0, 0><<<dim3(2, 4, 32), 256, 0, stream>>>(fr, Ws1, part, nullptr,
                                                        256, 512, 12288, 384, nullptr);
    reduce_bias<1, 1><<<128, 256, 0, stream>>>(part, bs1, t1, 131072, 512, 32);
    mfma_gemm<2, 0><<<dim3(2, 96, 1), 256, 0, stream>>>(t1, Ws2, spec, bs2,
                                                        256, 12288, 512, 512, nullptr);

    // neural_operator
    mfma_gemm<0, 0><<<dim3(2, 4, 32), 256, 0, stream>>>(spec, Wn1, part, nullptr,
                                                        256, 512, 12288, 384, nullptr);
    reduce_bias<1, 1><<<128, 256, 0, stream>>>(part, bn1, h1, 131072, 512, 32);
    mfma_gemm<0, 0><<<dim3(2, 4, 8), 256, 0, stream>>>(h1, Wn2, part, nullptr,
                                                       256, 512, 512, 64, nullptr);
    reduce_bias<1, 1><<<128, 256, 0, stream>>>(part, bn2, h2, 131072, 512, 8);
    mfma_gemm<3, 0><<<dim3(2, 96, 1), 256, 0, stream>>>(h2, Wn3, ph, bn3,
                                                        256, 12288, 512, 512, pl);

    // inverse fft2 real part (hi/lo bf16 in, f32 out, scale 1/4096)
    dft_mfma<1><<<NIMG, 256, 0, stream>>>(ph, pl, Tch, Tcl, Tsh, Tsl, out, nullptr);
}

// Round 6
// 191.949 us; speedup vs baseline: 2.9193x; 1.0577x over previous
//
#include <hip/hip_runtime.h>
#include <hip/hip_bf16.h>

#define NTOT 3145728   // 256*3*64*64
#define NIMG 768       // 256*3
#define CTAPS 1024     // GL conv truncation
#define NBAND 66       // conv bands: d = -1 .. 64

typedef __attribute__((ext_vector_type(8)))  short bf16x8;
typedef __attribute__((ext_vector_type(4)))  short bf16x4;
typedef __attribute__((ext_vector_type(8)))  unsigned short u16x8;
typedef __attribute__((ext_vector_type(4)))  unsigned short u16x4;
typedef __attribute__((ext_vector_type(4)))  float f32x4;
typedef __attribute__((ext_vector_type(16))) float f32x16;

__device__ inline unsigned short f2bf(float x) {
    unsigned u = __builtin_bit_cast(unsigned, x);
    u += 0x7fffu + ((u >> 16) & 1u);
    return (unsigned short)(u >> 16);
}
__device__ inline float bf2f(unsigned short u) {
    return __builtin_bit_cast(float, (unsigned)u << 16);
}
__device__ inline void split2(float v, unsigned short& hi, unsigned short& lo) {
    hi = f2bf(v);
    lo = f2bf(v - bf2f(hi));
}
__device__ inline bf16x8 ld2(const unsigned short* p) {   // 8B-aligned LDS read
    bf16x4 a = *(const bf16x4*)p;
    bf16x4 b = *(const bf16x4*)(p + 4);
    bf16x8 r;
    #pragma unroll
    for (int i = 0; i < 4; ++i) { r[i] = a[i]; r[4 + i] = b[i]; }
    return r;
}

// ---------------------------------------------------------------- tables ----
// 8 blocks: all recompute the 1024-tap weight scan; block 0 fills T tables +
// zero prefixes; every block fills a 1/8 stripe of the band matrices.
__global__ __launch_bounds__(1024)
void gen_tables(unsigned short* __restrict__ Tch, unsigned short* __restrict__ Tcl,
                unsigned short* __restrict__ Tsh, unsigned short* __restrict__ Tsl,
                unsigned short* __restrict__ Bth, unsigned short* __restrict__ Btl,
                unsigned short* __restrict__ fph, unsigned short* __restrict__ fpl)
{
    __shared__ float wsm[CTAPS];
    const int tid = threadIdx.x;
    const int bid = blockIdx.x;
    if (bid == 0) {
        const float step = 6.28318530717958647692f / 64.0f;
        for (int i = tid; i < 4096; i += 1024) {
            int p = i >> 6, q = i & 63;
            float ang = (float)((p * q) & 63) * step;
            unsigned short h, l;
            split2(cosf(ang), h, l); Tch[i] = h; Tcl[i] = l;
            split2(sinf(ang), h, l); Tsh[i] = h; Tsl[i] = l;
        }
        fph[tid] = 0; fpl[tid] = 0;   // 1024-element zero prefixes
    }
    // w[j] = h^{-alpha} * cumprod_{i=1..j} ((i-1.5)/i) via chunked wave scan
    if (tid < 64) {
        const int l = tid;
        float vals[16];
        float local = 1.0f;
        #pragma unroll
        for (int m = 0; m < 16; ++m) {
            int j = 16 * l + 1 + m;
            local *= ((float)j - 1.5f) / (float)j;
            vals[m] = local;
        }
        float scan = local;
        #pragma unroll
        for (int d = 1; d < 64; d <<= 1) {
            float o = __shfl_up(scan, (unsigned)d, 64);
            if (l >= d) scan *= o;
        }
        float prefix = __shfl_up(scan, 1u, 64);
        if (l == 0) prefix = 1.0f;
        const float s = sqrtf((float)(NTOT - 1));
        if (l == 0) wsm[0] = s;
        #pragma unroll
        for (int m = 0; m < 16; ++m) {
            int j = 16 * l + 1 + m;
            if (j < CTAPS) wsm[j] = prefix * vals[m] * s;
        }
    }
    __syncthreads();
    const int i0 = bid * 4224;                 // 66*512/8 = 4224 per block
    for (int i = i0 + tid; i < i0 + 4224; i += 1024) {
        int d = (i >> 9) - 1, o = (i >> 4) & 31, u = i & 15;
        int j = 16 * d + o - u;
        unsigned short h = 0, l = 0;
        if (j >= 0 && j < CTAPS) split2(wsm[j], h, l);
        Bth[i] = h; Btl[i] = l;
    }
}

// ---------------------------------------------------------- MFMA 2-D DFT ---
// One block per 64x64 image, 4 waves (one 32x32 quadrant each). hi/lo split
// operands, 3 accumulation chains (drops only lo*lo ~2^-18).
template<int INV>
__global__ __launch_bounds__(256)
void dft_mfma(const void* __restrict__ Xin, const unsigned short* __restrict__ Xlo_in,
              const unsigned short* __restrict__ Tch, const unsigned short* __restrict__ Tcl,
              const unsigned short* __restrict__ Tsh, const unsigned short* __restrict__ Tsl,
              void* __restrict__ Out, unsigned short* __restrict__ Out2)
{
    __shared__ __align__(16) unsigned short Xh[64 * 68], Xl[64 * 68];
    __shared__ __align__(16) unsigned short Chh[64 * 68], Cll[64 * 68];
    __shared__ __align__(16) unsigned short Shh[64 * 68], Sll[64 * 68];
    const int tid = threadIdx.x;
    const int img = blockIdx.x;
    {
        const int rr = tid >> 2, c0 = (tid & 3) * 16;
        const int lb = rr * 68 + c0;
        if (!INV) {
            const float* Xf = (const float*)Xin + (size_t)img * 4096 + rr * 64 + c0;
            #pragma unroll
            for (int i = 0; i < 4; ++i) {
                float4 v = *(const float4*)(Xf + 4 * i);
                float vv[4] = {v.x, v.y, v.z, v.w};
                #pragma unroll
                for (int k = 0; k < 4; ++k) {
                    unsigned short h, l; split2(vv[k], h, l);
                    Xh[lb + 4 * i + k] = h; Xl[lb + 4 * i + k] = l;
                }
            }
        } else {
            const unsigned short* Ph = (const unsigned short*)Xin + (size_t)img * 4096 + rr * 64 + c0;
            const unsigned short* Pl = Xlo_in + (size_t)img * 4096 + rr * 64 + c0;
            #pragma unroll
            for (int i = 0; i < 4; ++i) {
                *(ushort4*)&Xh[lb + 4 * i] = *(const ushort4*)(Ph + 4 * i);
                *(ushort4*)&Xl[lb + 4 * i] = *(const ushort4*)(Pl + 4 * i);
            }
        }
    }
    __syncthreads();

    const int lane = tid & 63, wv = tid >> 6;
    const int r = lane & 31, g = lane >> 5;
    const int q0 = (wv >> 1) * 32, r0 = (wv & 1) * 32;
    const int tA = (q0 + r) * 64;     // T row base (A operand)
    const int xB = (r0 + r) * 68;     // X / C / S row base (B operand)

    f32x16 a1, a2, a3;
    // ---- row pass, cos
    #pragma unroll
    for (int i = 0; i < 16; ++i) { a1[i] = 0.f; a2[i] = 0.f; a3[i] = 0.f; }
    #pragma unroll
    for (int ks = 0; ks < 4; ++ks) {
        const int ko = ks * 16 + 8 * g;
        bf16x8 xh = ld2(&Xh[xB + ko]);
        bf16x8 xl = ld2(&Xl[xB + ko]);
        bf16x8 th = *(const bf16x8*)&Tch[tA + ko];
        bf16x8 tl = *(const bf16x8*)&Tcl[tA + ko];
        a1 = __builtin_amdgcn_mfma_f32_32x32x16_bf16(th, xh, a1, 0, 0, 0);
        a2 = __builtin_amdgcn_mfma_f32_32x32x16_bf16(th, xl, a2, 0, 0, 0);
        a3 = __builtin_amdgcn_mfma_f32_32x32x16_bf16(tl, xh, a3, 0, 0, 0);
    }
    #pragma unroll
    for (int reg = 0; reg < 16; ++reg) {
        int qq = q0 + (reg & 3) + 8 * (reg >> 2) + 4 * g;
        unsigned short h, l; split2(a1[reg] + a2[reg] + a3[reg], h, l);
        Chh[qq * 68 + r0 + r] = h; Cll[qq * 68 + r0 + r] = l;
    }
    // ---- row pass, sin (stored negated)
    #pragma unroll
    for (int i = 0; i < 16; ++i) { a1[i] = 0.f; a2[i] = 0.f; a3[i] = 0.f; }
    #pragma unroll
    for (int ks = 0; ks < 4; ++ks) {
        const int ko = ks * 16 + 8 * g;
        bf16x8 xh = ld2(&Xh[xB + ko]);
        bf16x8 xl = ld2(&Xl[xB + ko]);
        bf16x8 th = *(const bf16x8*)&Tsh[tA + ko];
        bf16x8 tl = *(const bf16x8*)&Tsl[tA + ko];
        a1 = __builtin_amdgcn_mfma_f32_32x32x16_bf16(th, xh, a1, 0, 0, 0);
        a2 = __builtin_amdgcn_mfma_f32_32x32x16_bf16(th, xl, a2, 0, 0, 0);
        a3 = __builtin_amdgcn_mfma_f32_32x32x16_bf16(tl, xh, a3, 0, 0, 0);
    }
    #pragma unroll
    for (int reg = 0; reg < 16; ++reg) {
        int qq = q0 + (reg & 3) + 8 * (reg >> 2) + 4 * g;
        unsigned short h, l; split2(-(a1[reg] + a2[reg] + a3[reg]), h, l);
        Shh[qq * 68 + r0 + r] = h; Sll[qq * 68 + r0 + r] = l;
    }
    __syncthreads();

    // ---- col pass
    #pragma unroll
    for (int i = 0; i < 16; ++i) { a1[i] = 0.f; a2[i] = 0.f; a3[i] = 0.f; }
    #pragma unroll
    for (int ks = 0; ks < 4; ++ks) {
        const int ko = ks * 16 + 8 * g;
        bf16x8 ch = ld2(&Chh[xB + ko]);
        bf16x8 cl = ld2(&Cll[xB + ko]);
        bf16x8 th = *(const bf16x8*)&Tch[tA + ko];
        bf16x8 tl = *(const bf16x8*)&Tcl[tA + ko];
        a1 = __builtin_amdgcn_mfma_f32_32x32x16_bf16(th, ch, a1, 0, 0, 0);
        a2 = __builtin_amdgcn_mfma_f32_32x32x16_bf16(th, cl, a2, 0, 0, 0);
        a3 = __builtin_amdgcn_mfma_f32_32x32x16_bf16(tl, ch, a3, 0, 0, 0);
        bf16x8 sh = ld2(&Shh[xB + ko]);
        bf16x8 sl = ld2(&Sll[xB + ko]);
        bf16x8 uh = *(const bf16x8*)&Tsh[tA + ko];
        bf16x8 ul = *(const bf16x8*)&Tsl[tA + ko];
        a1 = __builtin_amdgcn_mfma_f32_32x32x16_bf16(uh, sh, a1, 0, 0, 0);
        a2 = __builtin_amdgcn_mfma_f32_32x32x16_bf16(uh, sl, a2, 0, 0, 0);
        a3 = __builtin_amdgcn_mfma_f32_32x32x16_bf16(ul, sh, a3, 0, 0, 0);
    }
    #pragma unroll
    for (int reg = 0; reg < 16; ++reg) {
        int pp = q0 + (reg & 3) + 8 * (reg >> 2) + 4 * g;
        float v = a1[reg] + a2[reg] + a3[reg];
        size_t oi = (size_t)img * 4096 + (size_t)pp * 64 + r0 + r;
        if (INV) {
            ((float*)Out)[oi] = v * (1.0f / 4096.0f);
        } else {
            unsigned short h, l; split2(v, h, l);
            ((unsigned short*)Out)[oi] = h; Out2[oi] = l;
        }
    }
}

// ----------------------------------------------------------- MFMA conv -----
// GL conv as banded block-GEMM, d = -1..64 (66 bands), hi/lo split, 3 chains.
// A window [tb0-1024, tb0+4096) staged once to LDS with a 16B-group XOR
// swizzle (gg ^= (gg>>3)&7) -> fragment reads are bank-balanced (8 phases).
// B (band matrices) read from global (L2-hot) with 2-deep register prefetch.
__global__ __launch_bounds__(256)
void conv_mfma(const unsigned short* __restrict__ fh, const unsigned short* __restrict__ fl,
               const unsigned short* __restrict__ Bth, const unsigned short* __restrict__ Btl,
               unsigned short* __restrict__ fr)
{
    __shared__ __align__(16) unsigned short Ah[5120], Al[5120];
    const int tid = threadIdx.x;
    const size_t tb0 = (size_t)blockIdx.x * 4096;
    {
        const unsigned short* sh = fh + tb0 - 1024;   // zero prefix covers block 0
        const unsigned short* sl = fl + tb0 - 1024;
        for (int gg = tid; gg < 640; gg += 256) {
            int off = (gg ^ ((gg >> 3) & 7)) << 3;    // swizzled element offset
            *(bf16x8*)&Ah[off] = *(const bf16x8*)(sh + gg * 8);
            *(bf16x8*)&Al[off] = *(const bf16x8*)(sl + gg * 8);
        }
    }
    __syncthreads();

    const int lane = tid & 63;
    const int wv = tid >> 6;
    const int r = lane & 31, g = lane >> 5;
    const int bo = 16 * r + 8 * g;
    const int base_gg = 128 * (wv + 1) + 4 * r + g + 2;   // A-frag group at dd=0

    f32x16 a1, a2, a3;
    #pragma unroll
    for (int i = 0; i < 16; ++i) { a1[i] = 0.f; a2[i] = 0.f; a3[i] = 0.f; }

    const unsigned short* bhp = Bth + bo;
    const unsigned short* blp = Btl + bo;
    bf16x8 bh0 = *(const bf16x8*)(bhp);
    bf16x8 bl0 = *(const bf16x8*)(blp);
    bf16x8 bh1 = *(const bf16x8*)(bhp + 512);
    bf16x8 bl1 = *(const bf16x8*)(blp + 512);

    for (int dd = 0; dd < NBAND; dd += 2) {
        bf16x8 nh0, nl0, nh1, nl1;
        if (dd + 2 < NBAND) {
            nh0 = *(const bf16x8*)(bhp + 512 * (dd + 2));
            nl0 = *(const bf16x8*)(blp + 512 * (dd + 2));
            nh1 = *(const bf16x8*)(bhp + 512 * (dd + 3));
            nl1 = *(const bf16x8*)(blp + 512 * (dd + 3));
        }
        {
            int gg = base_gg - 2 * dd;
            int off = (gg ^ ((gg >> 3) & 7)) << 3;
            bf16x8 avh = *(const bf16x8*)&Ah[off];
            bf16x8 avl = *(const bf16x8*)&Al[off];
            a1 = __builtin_amdgcn_mfma_f32_32x32x16_bf16(avh, bh0, a1, 0, 0, 0);
            a2 = __builtin_amdgcn_mfma_f32_32x32x16_bf16(avl, bh0, a2, 0, 0, 0);
            a3 = __builtin_amdgcn_mfma_f32_32x32x16_bf16(avh, bl0, a3, 0, 0, 0);
        }
        {
            int gg = base_gg - 2 * (dd + 1);
            int off = (gg ^ ((gg >> 3) & 7)) << 3;
            bf16x8 avh = *(const bf16x8*)&Ah[off];
            bf16x8 avl = *(const bf16x8*)&Al[off];
            a1 = __builtin_amdgcn_mfma_f32_32x32x16_bf16(avh, bh1, a1, 0, 0, 0);
            a2 = __builtin_amdgcn_mfma_f32_32x32x16_bf16(avl, bh1, a2, 0, 0, 0);
            a3 = __builtin_amdgcn_mfma_f32_32x32x16_bf16(avh, bl1, a3, 0, 0, 0);
        }
        bh0 = nh0; bl0 = nl0; bh1 = nh1; bl1 = nl1;
    }

    const size_t tb = tb0 + 1024 * wv;
    #pragma unroll
    for (int reg = 0; reg < 16; ++reg) {
        int row = (reg & 3) + 8 * (reg >> 2) + 4 * g;
        fr[tb + 32 * row + r] = f2bf(a1[reg] + a2[reg] + a3[reg]);
    }
}

// ------------------------------------------------------------- MFMA GEMM ----
// D = A(bf16, MxK row-major) @ W(f32, KxN row-major, converted inline).
// 128xBN tile (BN in {64,128}), 4 waves, BK=32, mfma_f32_16x16x32_bf16.
// MODE 0: f32 partial at Out + z*M*N.  MODE 1: f32 final (+bias).
// MODE 2: bf16 final (+bias).  MODE 3: bf16 hi/lo pair final (+bias).
template<int MODE, int RELU, int BN>
__global__ __launch_bounds__(256)
void mfma_gemm(const unsigned short* __restrict__ A, const float* __restrict__ W,
               void* __restrict__ Out, const float* __restrict__ bias,
               int M, int N, int K, int kChunk, unsigned short* __restrict__ Out2)
{
    constexpr int NE = (BN == 128) ? 8 : 4;   // staged k-rows per thread
    constexpr int N4 = BN / 32;               // B frags per wave
    __shared__ unsigned short Bs[BN * 40];
    const int tid = threadIdx.x;
    const int bm = blockIdx.x * 128;
    const int bn = blockIdx.y * BN;
    const int z  = blockIdx.z;
    const int kb0 = z * kChunk;
    const int nsteps = kChunk >> 5;

    const int lane = tid & 63;
    const int wv = tid >> 6;
    const int wr = (wv >> 1) * 64, wc = (wv & 1) * (BN / 2);
    const int l15 = lane & 15, l4 = lane >> 4;

    const int sn  = (BN == 128) ? (tid & 63) * 2 : (tid & 31) * 2;
    const int skq = (BN == 128) ? (tid >> 6) * 8 : (tid >> 5) * 4;

    f32x4 acc[4][N4];
    #pragma unroll
    for (int i = 0; i < 4; ++i)
        #pragma unroll
        for (int j = 0; j < N4; ++j)
            acc[i][j] = (f32x4){0.f, 0.f, 0.f, 0.f};

    float2 breg[NE];
    auto loadB = [&](int kb) {
        const float* Wp = W + (size_t)(kb + skq) * N + bn + sn;
        #pragma unroll
        for (int e = 0; e < NE; ++e)
            breg[e] = *(const float2*)(Wp + (size_t)e * N);
    };
    auto writeB = [&]() {
        if (BN == 128) {
            u16x8 p0, p1;
            #pragma unroll
            for (int e = 0; e < NE; ++e) { p0[e] = f2bf(breg[e].x); p1[e] = f2bf(breg[e].y); }
            *(u16x8*)&Bs[sn * 40 + skq]       = p0;
            *(u16x8*)&Bs[(sn + 1) * 40 + skq] = p1;
        } else {
            u16x4 p0, p1;
            #pragma unroll
            for (int e = 0; e < NE; ++e) { p0[e] = f2bf(breg[e].x); p1[e] = f2bf(breg[e].y); }
            *(u16x4*)&Bs[sn * 40 + skq]       = p0;
            *(u16x4*)&Bs[(sn + 1) * 40 + skq] = p1;
        }
    };

    loadB(kb0);
    writeB();
    __syncthreads();

    for (int step = 0; step < nsteps; ++step) {
        const int kb = kb0 + step * 32;
        bf16x8 fa[4], fb2[N4];
        const unsigned short* Ap = A + (size_t)(bm + wr + l15) * K + kb + l4 * 8;
        #pragma unroll
        for (int m4 = 0; m4 < 4; ++m4)
            fa[m4] = *(const bf16x8*)(Ap + (size_t)m4 * 16 * K);
        if (step + 1 < nsteps) loadB(kb + 32);
        #pragma unroll
        for (int n4 = 0; n4 < N4; ++n4)
            fb2[n4] = *(const bf16x8*)&Bs[(wc + n4 * 16 + l15) * 40 + l4 * 8];
        #pragma unroll
        for (int m4 = 0; m4 < 4; ++m4)
            #pragma unroll
            for (int n4 = 0; n4 < N4; ++n4)
                acc[m4][n4] = __builtin_amdgcn_mfma_f32_16x16x32_bf16(
                    fa[m4], fb2[n4], acc[m4][n4], 0, 0, 0);
        __syncthreads();
        if (step + 1 < nsteps) { writeB(); }
        __syncthreads();
    }

    #pragma unroll
    for (int m4 = 0; m4 < 4; ++m4)
        #pragma unroll
        for (int n4 = 0; n4 < N4; ++n4) {
            const int col = bn + wc + n4 * 16 + l15;
            const int row0 = bm + wr + m4 * 16 + l4 * 4;
            #pragma unroll
            for (int rg = 0; rg < 4; ++rg) {
                float v = acc[m4][n4][rg];
                const size_t oi = (size_t)(row0 + rg) * N + col;
                if (MODE == 0) {
                    ((float*)Out)[(size_t)z * M * N + oi] = v;
                } else {
                    v += bias[col];
                    if (RELU) v = fmaxf(v, 0.f);
                    if (MODE == 1) {
                        ((float*)Out)[oi] = v;
                    } else if (MODE == 2) {
                        ((unsigned short*)Out)[oi] = f2bf(v);
                    } else {
                        unsigned short h, l; split2(v, h, l);
                        ((unsigned short*)Out)[oi] = h; Out2[oi] = l;
                    }
                }
            }
        }
}

// --------------------------------------------------------------- reduce -----
template<int RELU, int OUTBF>
__global__ __launch_bounds__(256)
void reduce_bias(const float* __restrict__ P, const float* __restrict__ bias,
                 void* __restrict__ C, int MN, int N, int S)
{
    const int idx4 = blockIdx.x * 256 + threadIdx.x;
    const int MN4 = MN >> 2;
    if (idx4 >= MN4) return;
    const float4* P4 = (const float4*)P;
    float4 a = P4[idx4];
    for (int zz = 1; zz < S; ++zz) {
        float4 b = P4[(size_t)zz * MN4 + idx4];
        a.x += b.x; a.y += b.y; a.z += b.z; a.w += b.w;
    }
    int n0 = (idx4 * 4) % N;
    a.x += bias[n0]; a.y += bias[n0 + 1]; a.z += bias[n0 + 2]; a.w += bias[n0 + 3];
    if (RELU) {
        a.x = fmaxf(a.x, 0.f); a.y = fmaxf(a.y, 0.f);
        a.z = fmaxf(a.z, 0.f); a.w = fmaxf(a.w, 0.f);
    }
    if (OUTBF) {
        ushort4 v = {f2bf(a.x), f2bf(a.y), f2bf(a.z), f2bf(a.w)};
        ((ushort4*)C)[idx4] = v;
    } else {
        ((float4*)C)[idx4] = a;
    }
}

// ---------------------------------------------------------------- launch ----
extern "C" void kernel_launch(void* const* d_in, const int* in_sizes, int n_in,
                              void* d_out, int out_size, void* d_ws, size_t ws_size,
                              hipStream_t stream)
{
    const float* x   = (const float*)d_in[0];
    const float* Ws1 = (const float*)d_in[1];
    const float* bs1 = (const float*)d_in[2];
    const float* Ws2 = (const float*)d_in[3];
    const float* bs2 = (const float*)d_in[4];
    const float* Wn1 = (const float*)d_in[5];
    const float* bn1 = (const float*)d_in[6];
    const float* Wn2 = (const float*)d_in[7];
    const float* bn2 = (const float*)d_in[8];
    const float* Wn3 = (const float*)d_in[9];
    const float* bn3 = (const float*)d_in[10];
    float* out = (float*)d_out;

    char* p = (char*)d_ws;
    auto alloc = [&](size_t bytes) { char* q = p; p += (bytes + 255) & ~(size_t)255; return q; };
    unsigned short* Tch = (unsigned short*)alloc(8192);
    unsigned short* Tcl = (unsigned short*)alloc(8192);
    unsigned short* Tsh = (unsigned short*)alloc(8192);
    unsigned short* Tsl = (unsigned short*)alloc(8192);
    unsigned short* Bth = (unsigned short*)alloc((size_t)NBAND * 512 * 2);
    unsigned short* Btl = (unsigned short*)alloc((size_t)NBAND * 512 * 2);
    unsigned short* fhb = (unsigned short*)alloc((size_t)(1024 + NTOT) * 2);
    unsigned short* flb = (unsigned short*)alloc((size_t)(1024 + NTOT) * 2);
    unsigned short* fr   = (unsigned short*)alloc((size_t)NTOT * 2);
    unsigned short* spec = (unsigned short*)alloc((size_t)NTOT * 2);
    unsigned short* ph   = (unsigned short*)alloc((size_t)NTOT * 2);
    unsigned short* pl   = (unsigned short*)alloc((size_t)NTOT * 2);
    unsigned short* t1   = (unsigned short*)alloc(262144);
    unsigned short* h1   = (unsigned short*)alloc(262144);
    unsigned short* h2   = (unsigned short*)alloc(262144);
    float* part          = (float*)alloc((size_t)32 * 131072 * 4);

    gen_tables<<<8, 1024, 0, stream>>>(Tch, Tcl, Tsh, Tsl, Bth, Btl, fhb, flb);

    // forward fft2 real part -> hi/lo bf16 f (offset 1024, zero prefix)
    dft_mfma<0><<<NIMG, 256, 0, stream>>>(x, nullptr, Tch, Tcl, Tsh, Tsl,
                                          fhb + 1024, flb + 1024);

    // GL fractional conv (banded block-GEMM, LDS-staged A) -> fr (bf16)
    conv_mfma<<<NTOT / 4096, 256, 0, stream>>>(fhb + 1024, flb + 1024, Bth, Btl, fr);

    // spectral_operator
    mfma_gemm<0, 0, 64><<<dim3(2, 8, 32), 256, 0, stream>>>(fr, Ws1, part, nullptr,
                                                            256, 512, 12288, 384, nullptr);
    reduce_bias<1, 1><<<128, 256, 0, stream>>>(part, bs1, t1, 131072, 512, 32);
    mfma_gemm<2, 0, 64><<<dim3(2, 192, 1), 256, 0, stream>>>(t1, Ws2, spec, bs2,
                                                             256, 12288, 512, 512, nullptr);

    // neural_operator
    mfma_gemm<0, 0, 64><<<dim3(2, 8, 32), 256, 0, stream>>>(spec, Wn1, part, nullptr,
                                                            256, 512, 12288, 384, nullptr);
    reduce_bias<1, 1><<<128, 256, 0, stream>>>(part, bn1, h1, 131072, 512, 32);
    mfma_gemm<0, 0, 64><<<dim3(2, 8, 16), 256, 0, stream>>>(h1, Wn2, part, nullptr,
                                                            256, 512, 512, 32, nullptr);
    reduce_bias<1, 1><<<128, 256, 0, stream>>>(part, bn2, h2, 131072, 512, 16);
    mfma_gemm<3, 0, 64><<<dim3(2, 192, 1), 256, 0, stream>>>(h2, Wn3, ph, bn3,
                                                             256, 12288, 512, 512, pl);

    // inverse fft2 real part (hi/lo bf16 in, f32 out, scale 1/4096)
    dft_mfma<1><<<NIMG, 256, 0, stream>>>(ph, pl, Tch, Tcl, Tsh, Tsl, out, nullptr);
}

// Round 7
// 187.197 us; speedup vs baseline: 2.9934x; 1.0254x over previous
//
#include <hip/hip_runtime.h>
#include <hip/hip_bf16.h>

#define NTOT 3145728   // 256*3*64*64
#define NIMG 768       // 256*3
#define CTAPS 1024     // GL conv truncation
#define NBAND 66       // conv bands: d = -1 .. 64

typedef __attribute__((ext_vector_type(8)))  short bf16x8;
typedef __attribute__((ext_vector_type(4)))  short bf16x4;
typedef __attribute__((ext_vector_type(8)))  unsigned short u16x8;
typedef __attribute__((ext_vector_type(4)))  unsigned short u16x4;
typedef __attribute__((ext_vector_type(4)))  float f32x4;
typedef __attribute__((ext_vector_type(16))) float f32x16;

__device__ inline unsigned short f2bf(float x) {
    unsigned u = __builtin_bit_cast(unsigned, x);
    u += 0x7fffu + ((u >> 16) & 1u);
    return (unsigned short)(u >> 16);
}
__device__ inline float bf2f(unsigned short u) {
    return __builtin_bit_cast(float, (unsigned)u << 16);
}
__device__ inline void split2(float v, unsigned short& hi, unsigned short& lo) {
    hi = f2bf(v);
    lo = f2bf(v - bf2f(hi));
}
__device__ inline bf16x8 ld2(const unsigned short* p) {   // 8B-aligned LDS read
    bf16x4 a = *(const bf16x4*)p;
    bf16x4 b = *(const bf16x4*)(p + 4);
    bf16x8 r;
    #pragma unroll
    for (int i = 0; i < 4; ++i) { r[i] = a[i]; r[4 + i] = b[i]; }
    return r;
}

// ---------------------------------------------------------------- tables ----
// 8 blocks: T tables striped 512 entries/block; weight scan recomputed per
// block (cheap); Bt band matrices striped; block 0 also zeroes the f prefix.
__global__ __launch_bounds__(1024)
void gen_tables(unsigned short* __restrict__ Tch, unsigned short* __restrict__ Tcl,
                unsigned short* __restrict__ Tsh, unsigned short* __restrict__ Tsl,
                unsigned short* __restrict__ Bth, unsigned short* __restrict__ Btl,
                unsigned short* __restrict__ fph, unsigned short* __restrict__ fpl)
{
    __shared__ float wsm[CTAPS];
    const int tid = threadIdx.x;
    const int bid = blockIdx.x;
    const float step = 6.28318530717958647692f / 64.0f;
    if (tid < 512) {
        int i = bid * 512 + tid;
        int p = i >> 6, q = i & 63;
        float ang = (float)((p * q) & 63) * step;
        unsigned short h, l;
        split2(cosf(ang), h, l); Tch[i] = h; Tcl[i] = l;
        split2(sinf(ang), h, l); Tsh[i] = h; Tsl[i] = l;
    }
    if (bid == 0) { fph[tid] = 0; fpl[tid] = 0; }   // 1024-element zero prefixes
    // w[j] = h^{-alpha} * cumprod_{i=1..j} ((i-1.5)/i) via chunked wave scan
    if (tid < 64) {
        const int l = tid;
        float vals[16];
        float local = 1.0f;
        #pragma unroll
        for (int m = 0; m < 16; ++m) {
            int j = 16 * l + 1 + m;
            local *= ((float)j - 1.5f) / (float)j;
            vals[m] = local;
        }
        float scan = local;
        #pragma unroll
        for (int d = 1; d < 64; d <<= 1) {
            float o = __shfl_up(scan, (unsigned)d, 64);
            if (l >= d) scan *= o;
        }
        float prefix = __shfl_up(scan, 1u, 64);
        if (l == 0) prefix = 1.0f;
        const float s = sqrtf((float)(NTOT - 1));
        if (l == 0) wsm[0] = s;
        #pragma unroll
        for (int m = 0; m < 16; ++m) {
            int j = 16 * l + 1 + m;
            if (j < CTAPS) wsm[j] = prefix * vals[m] * s;
        }
    }
    __syncthreads();
    const int i0 = bid * 4224;                 // 66*512/8 = 4224 per block
    for (int i = i0 + tid; i < i0 + 4224; i += 1024) {
        int d = (i >> 9) - 1, o = (i >> 4) & 31, u = i & 15;
        int j = 16 * d + o - u;
        unsigned short h = 0, l = 0;
        if (j >= 0 && j < CTAPS) split2(wsm[j], h, l);
        Bth[i] = h; Btl[i] = l;
    }
}

// ---------------------------------------------------------- MFMA 2-D DFT ---
// One block per 64x64 image, 4 waves (one 32x32 quadrant each). hi/lo split
// operands, 3 accumulation chains (drops only lo*lo ~2^-18).
template<int INV>
__global__ __launch_bounds__(256)
void dft_mfma(const void* __restrict__ Xin, const unsigned short* __restrict__ Xlo_in,
              const unsigned short* __restrict__ Tch, const unsigned short* __restrict__ Tcl,
              const unsigned short* __restrict__ Tsh, const unsigned short* __restrict__ Tsl,
              void* __restrict__ Out, unsigned short* __restrict__ Out2)
{
    __shared__ __align__(16) unsigned short Xh[64 * 68], Xl[64 * 68];
    __shared__ __align__(16) unsigned short Chh[64 * 68], Cll[64 * 68];
    __shared__ __align__(16) unsigned short Shh[64 * 68], Sll[64 * 68];
    const int tid = threadIdx.x;
    const int img = blockIdx.x;
    {
        const int rr = tid >> 2, c0 = (tid & 3) * 16;
        const int lb = rr * 68 + c0;
        if (!INV) {
            const float* Xf = (const float*)Xin + (size_t)img * 4096 + rr * 64 + c0;
            #pragma unroll
            for (int i = 0; i < 4; ++i) {
                float4 v = *(const float4*)(Xf + 4 * i);
                float vv[4] = {v.x, v.y, v.z, v.w};
                #pragma unroll
                for (int k = 0; k < 4; ++k) {
                    unsigned short h, l; split2(vv[k], h, l);
                    Xh[lb + 4 * i + k] = h; Xl[lb + 4 * i + k] = l;
                }
            }
        } else {
            const unsigned short* Ph = (const unsigned short*)Xin + (size_t)img * 4096 + rr * 64 + c0;
            const unsigned short* Pl = Xlo_in + (size_t)img * 4096 + rr * 64 + c0;
            #pragma unroll
            for (int i = 0; i < 4; ++i) {
                *(ushort4*)&Xh[lb + 4 * i] = *(const ushort4*)(Ph + 4 * i);
                *(ushort4*)&Xl[lb + 4 * i] = *(const ushort4*)(Pl + 4 * i);
            }
        }
    }
    __syncthreads();

    const int lane = tid & 63, wv = tid >> 6;
    const int r = lane & 31, g = lane >> 5;
    const int q0 = (wv >> 1) * 32, r0 = (wv & 1) * 32;
    const int tA = (q0 + r) * 64;     // T row base (A operand)
    const int xB = (r0 + r) * 68;     // X / C / S row base (B operand)

    f32x16 a1, a2, a3;
    // ---- row pass, cos
    #pragma unroll
    for (int i = 0; i < 16; ++i) { a1[i] = 0.f; a2[i] = 0.f; a3[i] = 0.f; }
    #pragma unroll
    for (int ks = 0; ks < 4; ++ks) {
        const int ko = ks * 16 + 8 * g;
        bf16x8 xh = ld2(&Xh[xB + ko]);
        bf16x8 xl = ld2(&Xl[xB + ko]);
        bf16x8 th = *(const bf16x8*)&Tch[tA + ko];
        bf16x8 tl = *(const bf16x8*)&Tcl[tA + ko];
        a1 = __builtin_amdgcn_mfma_f32_32x32x16_bf16(th, xh, a1, 0, 0, 0);
        a2 = __builtin_amdgcn_mfma_f32_32x32x16_bf16(th, xl, a2, 0, 0, 0);
        a3 = __builtin_amdgcn_mfma_f32_32x32x16_bf16(tl, xh, a3, 0, 0, 0);
    }
    #pragma unroll
    for (int reg = 0; reg < 16; ++reg) {
        int qq = q0 + (reg & 3) + 8 * (reg >> 2) + 4 * g;
        unsigned short h, l; split2(a1[reg] + a2[reg] + a3[reg], h, l);
        Chh[qq * 68 + r0 + r] = h; Cll[qq * 68 + r0 + r] = l;
    }
    // ---- row pass, sin (stored negated)
    #pragma unroll
    for (int i = 0; i < 16; ++i) { a1[i] = 0.f; a2[i] = 0.f; a3[i] = 0.f; }
    #pragma unroll
    for (int ks = 0; ks < 4; ++ks) {
        const int ko = ks * 16 + 8 * g;
        bf16x8 xh = ld2(&Xh[xB + ko]);
        bf16x8 xl = ld2(&Xl[xB + ko]);
        bf16x8 th = *(const bf16x8*)&Tsh[tA + ko];
        bf16x8 tl = *(const bf16x8*)&Tsl[tA + ko];
        a1 = __builtin_amdgcn_mfma_f32_32x32x16_bf16(th, xh, a1, 0, 0, 0);
        a2 = __builtin_amdgcn_mfma_f32_32x32x16_bf16(th, xl, a2, 0, 0, 0);
        a3 = __builtin_amdgcn_mfma_f32_32x32x16_bf16(tl, xh, a3, 0, 0, 0);
    }
    #pragma unroll
    for (int reg = 0; reg < 16; ++reg) {
        int qq = q0 + (reg & 3) + 8 * (reg >> 2) + 4 * g;
        unsigned short h, l; split2(-(a1[reg] + a2[reg] + a3[reg]), h, l);
        Shh[qq * 68 + r0 + r] = h; Sll[qq * 68 + r0 + r] = l;
    }
    __syncthreads();

    // ---- col pass
    #pragma unroll
    for (int i = 0; i < 16; ++i) { a1[i] = 0.f; a2[i] = 0.f; a3[i] = 0.f; }
    #pragma unroll
    for (int ks = 0; ks < 4; ++ks) {
        const int ko = ks * 16 + 8 * g;
        bf16x8 ch = ld2(&Chh[xB + ko]);
        bf16x8 cl = ld2(&Cll[xB + ko]);
        bf16x8 th = *(const bf16x8*)&Tch[tA + ko];
        bf16x8 tl = *(const bf16x8*)&Tcl[tA + ko];
        a1 = __builtin_amdgcn_mfma_f32_32x32x16_bf16(th, ch, a1, 0, 0, 0);
        a2 = __builtin_amdgcn_mfma_f32_32x32x16_bf16(th, cl, a2, 0, 0, 0);
        a3 = __builtin_amdgcn_mfma_f32_32x32x16_bf16(tl, ch, a3, 0, 0, 0);
        bf16x8 sh = ld2(&Shh[xB + ko]);
        bf16x8 sl = ld2(&Sll[xB + ko]);
        bf16x8 uh = *(const bf16x8*)&Tsh[tA + ko];
        bf16x8 ul = *(const bf16x8*)&Tsl[tA + ko];
        a1 = __builtin_amdgcn_mfma_f32_32x32x16_bf16(uh, sh, a1, 0, 0, 0);
        a2 = __builtin_amdgcn_mfma_f32_32x32x16_bf16(uh, sl, a2, 0, 0, 0);
        a3 = __builtin_amdgcn_mfma_f32_32x32x16_bf16(ul, sh, a3, 0, 0, 0);
    }
    #pragma unroll
    for (int reg = 0; reg < 16; ++reg) {
        int pp = q0 + (reg & 3) + 8 * (reg >> 2) + 4 * g;
        float v = a1[reg] + a2[reg] + a3[reg];
        size_t oi = (size_t)img * 4096 + (size_t)pp * 64 + r0 + r;
        if (INV) {
            ((float*)Out)[oi] = v * (1.0f / 4096.0f);
        } else {
            unsigned short h, l; split2(v, h, l);
            ((unsigned short*)Out)[oi] = h; Out2[oi] = l;
        }
    }
}

// ----------------------------------------------------------- MFMA conv -----
// GL conv as banded block-GEMM, d = -1..64 (66 bands), hi/lo split, 3 chains.
// A window staged to LDS with 16B-group XOR swizzle; B via 2-deep reg prefetch.
__global__ __launch_bounds__(256)
void conv_mfma(const unsigned short* __restrict__ fh, const unsigned short* __restrict__ fl,
               const unsigned short* __restrict__ Bth, const unsigned short* __restrict__ Btl,
               unsigned short* __restrict__ fr)
{
    __shared__ __align__(16) unsigned short Ah[5120], Al[5120];
    const int tid = threadIdx.x;
    const size_t tb0 = (size_t)blockIdx.x * 4096;
    {
        const unsigned short* sh = fh + tb0 - 1024;   // zero prefix covers block 0
        const unsigned short* sl = fl + tb0 - 1024;
        for (int gg = tid; gg < 640; gg += 256) {
            int off = (gg ^ ((gg >> 3) & 7)) << 3;    // swizzled element offset
            *(bf16x8*)&Ah[off] = *(const bf16x8*)(sh + gg * 8);
            *(bf16x8*)&Al[off] = *(const bf16x8*)(sl + gg * 8);
        }
    }
    __syncthreads();

    const int lane = tid & 63;
    const int wv = tid >> 6;
    const int r = lane & 31, g = lane >> 5;
    const int bo = 16 * r + 8 * g;
    const int base_gg = 128 * (wv + 1) + 4 * r + g + 2;   // A-frag group at dd=0

    f32x16 a1, a2, a3;
    #pragma unroll
    for (int i = 0; i < 16; ++i) { a1[i] = 0.f; a2[i] = 0.f; a3[i] = 0.f; }

    const unsigned short* bhp = Bth + bo;
    const unsigned short* blp = Btl + bo;
    bf16x8 bh0 = *(const bf16x8*)(bhp);
    bf16x8 bl0 = *(const bf16x8*)(blp);
    bf16x8 bh1 = *(const bf16x8*)(bhp + 512);
    bf16x8 bl1 = *(const bf16x8*)(blp + 512);

    for (int dd = 0; dd < NBAND; dd += 2) {
        bf16x8 nh0, nl0, nh1, nl1;
        if (dd + 2 < NBAND) {
            nh0 = *(const bf16x8*)(bhp + 512 * (dd + 2));
            nl0 = *(const bf16x8*)(blp + 512 * (dd + 2));
            nh1 = *(const bf16x8*)(bhp + 512 * (dd + 3));
            nl1 = *(const bf16x8*)(blp + 512 * (dd + 3));
        }
        {
            int gg = base_gg - 2 * dd;
            int off = (gg ^ ((gg >> 3) & 7)) << 3;
            bf16x8 avh = *(const bf16x8*)&Ah[off];
            bf16x8 avl = *(const bf16x8*)&Al[off];
            a1 = __builtin_amdgcn_mfma_f32_32x32x16_bf16(avh, bh0, a1, 0, 0, 0);
            a2 = __builtin_amdgcn_mfma_f32_32x32x16_bf16(avl, bh0, a2, 0, 0, 0);
            a3 = __builtin_amdgcn_mfma_f32_32x32x16_bf16(avh, bl0, a3, 0, 0, 0);
        }
        {
            int gg = base_gg - 2 * (dd + 1);
            int off = (gg ^ ((gg >> 3) & 7)) << 3;
            bf16x8 avh = *(const bf16x8*)&Ah[off];
            bf16x8 avl = *(const bf16x8*)&Al[off];
            a1 = __builtin_amdgcn_mfma_f32_32x32x16_bf16(avh, bh1, a1, 0, 0, 0);
            a2 = __builtin_amdgcn_mfma_f32_32x32x16_bf16(avl, bh1, a2, 0, 0, 0);
            a3 = __builtin_amdgcn_mfma_f32_32x32x16_bf16(avh, bl1, a3, 0, 0, 0);
        }
        bh0 = nh0; bl0 = nl0; bh1 = nh1; bl1 = nl1;
    }

    const size_t tb = tb0 + 1024 * wv;
    #pragma unroll
    for (int reg = 0; reg < 16; ++reg) {
        int row = (reg & 3) + 8 * (reg >> 2) + 4 * g;
        fr[tb + 32 * row + r] = f2bf(a1[reg] + a2[reg] + a3[reg]);
    }
}

// ------------------------------------------------------------- MFMA GEMM ----
// D = A(bf16, MxK row-major) @ W(f32, KxN row-major, converted inline).
// 128xBN tile, 4 waves, BK=32, mfma_f32_16x16x32_bf16.
// Double-buffered LDS (one barrier per K-step) + reg-prefetched A and W.
// 1-D grid with XCD pairing: ids p and p+8 (same XCD, round-robin) are the
// two bm-blocks sharing one W panel -> W fetched once per XCD-L2.
// MODE 0: f32 partial at Out + z*M*N.  MODE 1: f32 final (+bias).
// MODE 2: bf16 final (+bias).  MODE 3: bf16 hi/lo pair final (+bias).
template<int MODE, int RELU, int BN>
__global__ __launch_bounds__(256)
void mfma_gemm(const unsigned short* __restrict__ A, const float* __restrict__ W,
               void* __restrict__ Out, const float* __restrict__ bias,
               int M, int N, int K, int kChunk, int nbn,
               unsigned short* __restrict__ Out2)
{
    constexpr int NE = (BN == 128) ? 8 : 4;   // staged k-rows per thread
    constexpr int N4 = BN / 32;               // B frags per wave
    __shared__ unsigned short Bs[2][BN * 40];
    const int tid = threadIdx.x;
    // decode: g = id>>4 selects a group of 8 (bn,z) tiles; r&7 = tile-in-group
    // (lands on XCD r&7); r>>3 = bm half, 8 ids apart -> same XCD.
    const int id = blockIdx.x;
    const int gq = id >> 4, rr = id & 15;
    const int t  = gq * 8 + (rr & 7);
    const int bm = (rr >> 3) * 128;
    const int bn = (t % nbn) * BN;
    const int z  = t / nbn;
    const int kb0 = z * kChunk;
    const int nsteps = kChunk >> 5;

    const int lane = tid & 63;
    const int wv = tid >> 6;
    const int wr = (wv >> 1) * 64, wc = (wv & 1) * (BN / 2);
    const int l15 = lane & 15, l4 = lane >> 4;

    const int sn  = (BN == 128) ? (tid & 63) * 2 : (tid & 31) * 2;
    const int skq = (BN == 128) ? (tid >> 6) * 8 : (tid >> 5) * 4;

    f32x4 acc[4][N4];
    #pragma unroll
    for (int i = 0; i < 4; ++i)
        #pragma unroll
        for (int j = 0; j < N4; ++j)
            acc[i][j] = (f32x4){0.f, 0.f, 0.f, 0.f};

    float2 breg[NE];
    auto loadB = [&](int kb) {
        const float* Wp = W + (size_t)(kb + skq) * N + bn + sn;
        #pragma unroll
        for (int e = 0; e < NE; ++e)
            breg[e] = *(const float2*)(Wp + (size_t)e * N);
    };
    auto writeB = [&](int b) {
        if (BN == 128) {
            u16x8 p0, p1;
            #pragma unroll
            for (int e = 0; e < NE; ++e) { p0[e] = f2bf(breg[e].x); p1[e] = f2bf(breg[e].y); }
            *(u16x8*)&Bs[b][sn * 40 + skq]       = p0;
            *(u16x8*)&Bs[b][(sn + 1) * 40 + skq] = p1;
        } else {
            u16x4 p0, p1;
            #pragma unroll
            for (int e = 0; e < NE; ++e) { p0[e] = f2bf(breg[e].x); p1[e] = f2bf(breg[e].y); }
            *(u16x4*)&Bs[b][sn * 40 + skq]       = p0;
            *(u16x4*)&Bs[b][(sn + 1) * 40 + skq] = p1;
        }
    };

    const unsigned short* Arow = A + (size_t)(bm + wr + l15) * K + l4 * 8;
    bf16x8 faA[4], faN[4];

    loadB(kb0);
    writeB(0);
    #pragma unroll
    for (int m4 = 0; m4 < 4; ++m4)
        faA[m4] = *(const bf16x8*)(Arow + kb0 + (size_t)m4 * 16 * K);
    __syncthreads();

    int cur = 0;
    for (int step = 0; step < nsteps; ++step) {
        const int kb = kb0 + step * 32;
        if (step + 1 < nsteps) {
            loadB(kb + 32);
            #pragma unroll
            for (int m4 = 0; m4 < 4; ++m4)
                faN[m4] = *(const bf16x8*)(Arow + kb + 32 + (size_t)m4 * 16 * K);
        }
        bf16x8 fb2[N4];
        #pragma unroll
        for (int n4 = 0; n4 < N4; ++n4)
            fb2[n4] = *(const bf16x8*)&Bs[cur][(wc + n4 * 16 + l15) * 40 + l4 * 8];
        #pragma unroll
        for (int m4 = 0; m4 < 4; ++m4)
            #pragma unroll
            for (int n4 = 0; n4 < N4; ++n4)
                acc[m4][n4] = __builtin_amdgcn_mfma_f32_16x16x32_bf16(
                    faA[m4], fb2[n4], acc[m4][n4], 0, 0, 0);
        if (step + 1 < nsteps) writeB(cur ^ 1);
        __syncthreads();
        #pragma unroll
        for (int m4 = 0; m4 < 4; ++m4) faA[m4] = faN[m4];
        cur ^= 1;
    }

    #pragma unroll
    for (int m4 = 0; m4 < 4; ++m4)
        #pragma unroll
        for (int n4 = 0; n4 < N4; ++n4) {
            const int col = bn + wc + n4 * 16 + l15;
            const int row0 = bm + wr + m4 * 16 + l4 * 4;
            #pragma unroll
            for (int rg = 0; rg < 4; ++rg) {
                float v = acc[m4][n4][rg];
                const size_t oi = (size_t)(row0 + rg) * N + col;
                if (MODE == 0) {
                    ((float*)Out)[(size_t)z * M * N + oi] = v;
                } else {
                    v += bias[col];
                    if (RELU) v = fmaxf(v, 0.f);
                    if (MODE == 1) {
                        ((float*)Out)[oi] = v;
                    } else if (MODE == 2) {
                        ((unsigned short*)Out)[oi] = f2bf(v);
                    } else {
                        unsigned short h, l; split2(v, h, l);
                        ((unsigned short*)Out)[oi] = h; Out2[oi] = l;
                    }
                }
            }
        }
}

// --------------------------------------------------------------- reduce -----
template<int RELU, int OUTBF>
__global__ __launch_bounds__(256)
void reduce_bias(const float* __restrict__ P, const float* __restrict__ bias,
                 void* __restrict__ C, int MN, int N, int S)
{
    const int idx4 = blockIdx.x * 256 + threadIdx.x;
    const int MN4 = MN >> 2;
    if (idx4 >= MN4) return;
    const float4* P4 = (const float4*)P;
    float4 a = P4[idx4];
    for (int zz = 1; zz < S; ++zz) {
        float4 b = P4[(size_t)zz * MN4 + idx4];
        a.x += b.x; a.y += b.y; a.z += b.z; a.w += b.w;
    }
    int n0 = (idx4 * 4) % N;
    a.x += bias[n0]; a.y += bias[n0 + 1]; a.z += bias[n0 + 2]; a.w += bias[n0 + 3];
    if (RELU) {
        a.x = fmaxf(a.x, 0.f); a.y = fmaxf(a.y, 0.f);
        a.z = fmaxf(a.z, 0.f); a.w = fmaxf(a.w, 0.f);
    }
    if (OUTBF) {
        ushort4 v = {f2bf(a.x), f2bf(a.y), f2bf(a.z), f2bf(a.w)};
        ((ushort4*)C)[idx4] = v;
    } else {
        ((float4*)C)[idx4] = a;
    }
}

// ---------------------------------------------------------------- launch ----
extern "C" void kernel_launch(void* const* d_in, const int* in_sizes, int n_in,
                              void* d_out, int out_size, void* d_ws, size_t ws_size,
                              hipStream_t stream)
{
    const float* x   = (const float*)d_in[0];
    const float* Ws1 = (const float*)d_in[1];
    const float* bs1 = (const float*)d_in[2];
    const float* Ws2 = (const float*)d_in[3];
    const float* bs2 = (const float*)d_in[4];
    const float* Wn1 = (const float*)d_in[5];
    const float* bn1 = (const float*)d_in[6];
    const float* Wn2 = (const float*)d_in[7];
    const float* bn2 = (const float*)d_in[8];
    const float* Wn3 = (const float*)d_in[9];
    const float* bn3 = (const float*)d_in[10];
    float* out = (float*)d_out;

    char* p = (char*)d_ws;
    auto alloc = [&](size_t bytes) { char* q = p; p += (bytes + 255) & ~(size_t)255; return q; };
    unsigned short* Tch = (unsigned short*)alloc(8192);
    unsigned short* Tcl = (unsigned short*)alloc(8192);
    unsigned short* Tsh = (unsigned short*)alloc(8192);
    unsigned short* Tsl = (unsigned short*)alloc(8192);
    unsigned short* Bth = (unsigned short*)alloc((size_t)NBAND * 512 * 2);
    unsigned short* Btl = (unsigned short*)alloc((size_t)NBAND * 512 * 2);
    unsigned short* fhb = (unsigned short*)alloc((size_t)(1024 + NTOT) * 2);
    unsigned short* flb = (unsigned short*)alloc((size_t)(1024 + NTOT) * 2);
    unsigned short* fr   = (unsigned short*)alloc((size_t)NTOT * 2);
    unsigned short* spec = (unsigned short*)alloc((size_t)NTOT * 2);
    unsigned short* ph   = (unsigned short*)alloc((size_t)NTOT * 2);
    unsigned short* pl   = (unsigned short*)alloc((size_t)NTOT * 2);
    unsigned short* t1   = (unsigned short*)alloc(262144);
    unsigned short* h1   = (unsigned short*)alloc(262144);
    unsigned short* h2   = (unsigned short*)alloc(262144);
    float* part          = (float*)alloc((size_t)16 * 131072 * 4);

    gen_tables<<<8, 1024, 0, stream>>>(Tch, Tcl, Tsh, Tsl, Bth, Btl, fhb, flb);

    // forward fft2 real part -> hi/lo bf16 f (offset 1024, zero prefix)
    dft_mfma<0><<<NIMG, 256, 0, stream>>>(x, nullptr, Tch, Tcl, Tsh, Tsl,
                                          fhb + 1024, flb + 1024);

    // GL fractional conv (banded block-GEMM, LDS-staged A) -> fr (bf16)
    conv_mfma<<<NTOT / 4096, 256, 0, stream>>>(fhb + 1024, flb + 1024, Bth, Btl, fr);

    // spectral_operator: L1 (split-K z=16) + reduce, L2 (N=12288)
    mfma_gemm<0, 0, 64><<<256, 256, 0, stream>>>(fr, Ws1, part, nullptr,
                                                 256, 512, 12288, 768, 8, nullptr);
    reduce_bias<1, 1><<<128, 256, 0, stream>>>(part, bs1, t1, 131072, 512, 16);
    mfma_gemm<2, 0, 64><<<384, 256, 0, stream>>>(t1, Ws2, spec, bs2,
                                                 256, 12288, 512, 512, 192, nullptr);

    // neural_operator: L3 + reduce, L4 (z=8) + reduce, L5 (N=12288, hi/lo out)
    mfma_gemm<0, 0, 64><<<256, 256, 0, stream>>>(spec, Wn1, part, nullptr,
                                                 256, 512, 12288, 768, 8, nullptr);
    reduce_bias<1, 1><<<128, 256, 0, stream>>>(part, bn1, h1, 131072, 512, 16);
    mfma_gemm<0, 0, 64><<<128, 256, 0, stream>>>(h1, Wn2, part, nullptr,
                                                 256, 512, 512, 64, 8, nullptr);
    reduce_bias<1, 1><<<128, 256, 0, stream>>>(part, bn2, h2, 131072, 512, 8);
    mfma_gemm<3, 0, 64><<<384, 256, 0, stream>>>(h2, Wn3, ph, bn3,
                                                 256, 12288, 512, 512, 192, pl);

    // inverse fft2 real part (hi/lo bf16 in, f32 out, scale 1/4096)
    dft_mfma<1><<<NIMG, 256, 0, stream>>>(ph, pl, Tch, Tcl, Tsh, Tsl, out, nullptr);
}

// Round 8
// 168.118 us; speedup vs baseline: 3.3331x; 1.1135x over previous
//
#include <hip/hip_runtime.h>
#include <hip/hip_bf16.h>

#define NTOT 3145728   // 256*3*64*64
#define NIMG 768       // 256*3
#define CTAPS 1024     // GL conv truncation
#define NBAND 66       // conv bands: d = -1 .. 64

typedef __attribute__((ext_vector_type(8)))  short bf16x8;
typedef __attribute__((ext_vector_type(4)))  short bf16x4;
typedef __attribute__((ext_vector_type(8)))  unsigned short u16x8;
typedef __attribute__((ext_vector_type(4)))  unsigned short u16x4;
typedef __attribute__((ext_vector_type(4)))  float f32x4;
typedef __attribute__((ext_vector_type(16))) float f32x16;

__device__ inline unsigned short f2bf(float x) {
    unsigned u = __builtin_bit_cast(unsigned, x);
    u += 0x7fffu + ((u >> 16) & 1u);
    return (unsigned short)(u >> 16);
}
__device__ inline float bf2f(unsigned short u) {
    return __builtin_bit_cast(float, (unsigned)u << 16);
}
__device__ inline void split2(float v, unsigned short& hi, unsigned short& lo) {
    hi = f2bf(v);
    lo = f2bf(v - bf2f(hi));
}
__device__ inline bf16x8 ld2(const unsigned short* p) {   // 8B-aligned LDS read
    bf16x4 a = *(const bf16x4*)p;
    bf16x4 b = *(const bf16x4*)(p + 4);
    bf16x8 r;
    #pragma unroll
    for (int i = 0; i < 4; ++i) { r[i] = a[i]; r[4 + i] = b[i]; }
    return r;
}

// ---------------------------------------------------------------- tables ----
__global__ __launch_bounds__(1024)
void gen_tables(unsigned short* __restrict__ Tch, unsigned short* __restrict__ Tcl,
                unsigned short* __restrict__ Tsh, unsigned short* __restrict__ Tsl,
                unsigned short* __restrict__ Bth, unsigned short* __restrict__ Btl,
                unsigned short* __restrict__ fph, unsigned short* __restrict__ fpl)
{
    __shared__ float wsm[CTAPS];
    const int tid = threadIdx.x;
    const int bid = blockIdx.x;
    const float step = 6.28318530717958647692f / 64.0f;
    if (tid < 512) {
        int i = bid * 512 + tid;
        int p = i >> 6, q = i & 63;
        float ang = (float)((p * q) & 63) * step;
        unsigned short h, l;
        split2(cosf(ang), h, l); Tch[i] = h; Tcl[i] = l;
        split2(sinf(ang), h, l); Tsh[i] = h; Tsl[i] = l;
    }
    if (bid == 0) { fph[tid] = 0; fpl[tid] = 0; }   // 1024-element zero prefixes
    if (tid < 64) {
        const int l = tid;
        float vals[16];
        float local = 1.0f;
        #pragma unroll
        for (int m = 0; m < 16; ++m) {
            int j = 16 * l + 1 + m;
            local *= ((float)j - 1.5f) / (float)j;
            vals[m] = local;
        }
        float scan = local;
        #pragma unroll
        for (int d = 1; d < 64; d <<= 1) {
            float o = __shfl_up(scan, (unsigned)d, 64);
            if (l >= d) scan *= o;
        }
        float prefix = __shfl_up(scan, 1u, 64);
        if (l == 0) prefix = 1.0f;
        const float s = sqrtf((float)(NTOT - 1));
        if (l == 0) wsm[0] = s;
        #pragma unroll
        for (int m = 0; m < 16; ++m) {
            int j = 16 * l + 1 + m;
            if (j < CTAPS) wsm[j] = prefix * vals[m] * s;
        }
    }
    __syncthreads();
    const int i0 = bid * 4224;                 // 66*512/8 = 4224 per block
    for (int i = i0 + tid; i < i0 + 4224; i += 1024) {
        int d = (i >> 9) - 1, o = (i >> 4) & 31, u = i & 15;
        int j = 16 * d + o - u;
        unsigned short h = 0, l = 0;
        if (j >= 0 && j < CTAPS) split2(wsm[j], h, l);
        Bth[i] = h; Btl[i] = l;
    }
}

// ---------------------------------------------------------- MFMA 2-D DFT ---
template<int INV>
__global__ __launch_bounds__(256)
void dft_mfma(const void* __restrict__ Xin, const unsigned short* __restrict__ Xlo_in,
              const unsigned short* __restrict__ Tch, const unsigned short* __restrict__ Tcl,
              const unsigned short* __restrict__ Tsh, const unsigned short* __restrict__ Tsl,
              void* __restrict__ Out, unsigned short* __restrict__ Out2)
{
    __shared__ __align__(16) unsigned short Xh[64 * 68], Xl[64 * 68];
    __shared__ __align__(16) unsigned short Chh[64 * 68], Cll[64 * 68];
    __shared__ __align__(16) unsigned short Shh[64 * 68], Sll[64 * 68];
    const int tid = threadIdx.x;
    const int img = blockIdx.x;
    {
        const int rr = tid >> 2, c0 = (tid & 3) * 16;
        const int lb = rr * 68 + c0;
        if (!INV) {
            const float* Xf = (const float*)Xin + (size_t)img * 4096 + rr * 64 + c0;
            #pragma unroll
            for (int i = 0; i < 4; ++i) {
                float4 v = *(const float4*)(Xf + 4 * i);
                float vv[4] = {v.x, v.y, v.z, v.w};
                #pragma unroll
                for (int k = 0; k < 4; ++k) {
                    unsigned short h, l; split2(vv[k], h, l);
                    Xh[lb + 4 * i + k] = h; Xl[lb + 4 * i + k] = l;
                }
            }
        } else {
            const unsigned short* Ph = (const unsigned short*)Xin + (size_t)img * 4096 + rr * 64 + c0;
            const unsigned short* Pl = Xlo_in + (size_t)img * 4096 + rr * 64 + c0;
            #pragma unroll
            for (int i = 0; i < 4; ++i) {
                *(ushort4*)&Xh[lb + 4 * i] = *(const ushort4*)(Ph + 4 * i);
                *(ushort4*)&Xl[lb + 4 * i] = *(const ushort4*)(Pl + 4 * i);
            }
        }
    }
    __syncthreads();

    const int lane = tid & 63, wv = tid >> 6;
    const int r = lane & 31, g = lane >> 5;
    const int q0 = (wv >> 1) * 32, r0 = (wv & 1) * 32;
    const int tA = (q0 + r) * 64;     // T row base (A operand)
    const int xB = (r0 + r) * 68;     // X / C / S row base (B operand)

    f32x16 a1, a2, a3;
    // ---- row pass, cos
    #pragma unroll
    for (int i = 0; i < 16; ++i) { a1[i] = 0.f; a2[i] = 0.f; a3[i] = 0.f; }
    #pragma unroll
    for (int ks = 0; ks < 4; ++ks) {
        const int ko = ks * 16 + 8 * g;
        bf16x8 xh = ld2(&Xh[xB + ko]);
        bf16x8 xl = ld2(&Xl[xB + ko]);
        bf16x8 th = *(const bf16x8*)&Tch[tA + ko];
        bf16x8 tl = *(const bf16x8*)&Tcl[tA + ko];
        a1 = __builtin_amdgcn_mfma_f32_32x32x16_bf16(th, xh, a1, 0, 0, 0);
        a2 = __builtin_amdgcn_mfma_f32_32x32x16_bf16(th, xl, a2, 0, 0, 0);
        a3 = __builtin_amdgcn_mfma_f32_32x32x16_bf16(tl, xh, a3, 0, 0, 0);
    }
    #pragma unroll
    for (int reg = 0; reg < 16; ++reg) {
        int qq = q0 + (reg & 3) + 8 * (reg >> 2) + 4 * g;
        unsigned short h, l; split2(a1[reg] + a2[reg] + a3[reg], h, l);
        Chh[qq * 68 + r0 + r] = h; Cll[qq * 68 + r0 + r] = l;
    }
    // ---- row pass, sin (stored negated)
    #pragma unroll
    for (int i = 0; i < 16; ++i) { a1[i] = 0.f; a2[i] = 0.f; a3[i] = 0.f; }
    #pragma unroll
    for (int ks = 0; ks < 4; ++ks) {
        const int ko = ks * 16 + 8 * g;
        bf16x8 xh = ld2(&Xh[xB + ko]);
        bf16x8 xl = ld2(&Xl[xB + ko]);
        bf16x8 th = *(const bf16x8*)&Tsh[tA + ko];
        bf16x8 tl = *(const bf16x8*)&Tsl[tA + ko];
        a1 = __builtin_amdgcn_mfma_f32_32x32x16_bf16(th, xh, a1, 0, 0, 0);
        a2 = __builtin_amdgcn_mfma_f32_32x32x16_bf16(th, xl, a2, 0, 0, 0);
        a3 = __builtin_amdgcn_mfma_f32_32x32x16_bf16(tl, xh, a3, 0, 0, 0);
    }
    #pragma unroll
    for (int reg = 0; reg < 16; ++reg) {
        int qq = q0 + (reg & 3) + 8 * (reg >> 2) + 4 * g;
        unsigned short h, l; split2(-(a1[reg] + a2[reg] + a3[reg]), h, l);
        Shh[qq * 68 + r0 + r] = h; Sll[qq * 68 + r0 + r] = l;
    }
    __syncthreads();

    // ---- col pass
    #pragma unroll
    for (int i = 0; i < 16; ++i) { a1[i] = 0.f; a2[i] = 0.f; a3[i] = 0.f; }
    #pragma unroll
    for (int ks = 0; ks < 4; ++ks) {
        const int ko = ks * 16 + 8 * g;
        bf16x8 ch = ld2(&Chh[xB + ko]);
        bf16x8 cl = ld2(&Cll[xB + ko]);
        bf16x8 th = *(const bf16x8*)&Tch[tA + ko];
        bf16x8 tl = *(const bf16x8*)&Tcl[tA + ko];
        a1 = __builtin_amdgcn_mfma_f32_32x32x16_bf16(th, ch, a1, 0, 0, 0);
        a2 = __builtin_amdgcn_mfma_f32_32x32x16_bf16(th, cl, a2, 0, 0, 0);
        a3 = __builtin_amdgcn_mfma_f32_32x32x16_bf16(tl, ch, a3, 0, 0, 0);
        bf16x8 sh = ld2(&Shh[xB + ko]);
        bf16x8 sl = ld2(&Sll[xB + ko]);
        bf16x8 uh = *(const bf16x8*)&Tsh[tA + ko];
        bf16x8 ul = *(const bf16x8*)&Tsl[tA + ko];
        a1 = __builtin_amdgcn_mfma_f32_32x32x16_bf16(uh, sh, a1, 0, 0, 0);
        a2 = __builtin_amdgcn_mfma_f32_32x32x16_bf16(uh, sl, a2, 0, 0, 0);
        a3 = __builtin_amdgcn_mfma_f32_32x32x16_bf16(ul, sh, a3, 0, 0, 0);
    }
    #pragma unroll
    for (int reg = 0; reg < 16; ++reg) {
        int pp = q0 + (reg & 3) + 8 * (reg >> 2) + 4 * g;
        float v = a1[reg] + a2[reg] + a3[reg];
        size_t oi = (size_t)img * 4096 + (size_t)pp * 64 + r0 + r;
        if (INV) {
            ((float*)Out)[oi] = v * (1.0f / 4096.0f);
        } else {
            unsigned short h, l; split2(v, h, l);
            ((unsigned short*)Out)[oi] = h; Out2[oi] = l;
        }
    }
}

// ----------------------------------------------------------- MFMA conv -----
__global__ __launch_bounds__(256)
void conv_mfma(const unsigned short* __restrict__ fh, const unsigned short* __restrict__ fl,
               const unsigned short* __restrict__ Bth, const unsigned short* __restrict__ Btl,
               unsigned short* __restrict__ fr)
{
    __shared__ __align__(16) unsigned short Ah[5120], Al[5120];
    const int tid = threadIdx.x;
    const size_t tb0 = (size_t)blockIdx.x * 4096;
    {
        const unsigned short* sh = fh + tb0 - 1024;   // zero prefix covers block 0
        const unsigned short* sl = fl + tb0 - 1024;
        for (int gg = tid; gg < 640; gg += 256) {
            int off = (gg ^ ((gg >> 3) & 7)) << 3;    // swizzled element offset
            *(bf16x8*)&Ah[off] = *(const bf16x8*)(sh + gg * 8);
            *(bf16x8*)&Al[off] = *(const bf16x8*)(sl + gg * 8);
        }
    }
    __syncthreads();

    const int lane = tid & 63;
    const int wv = tid >> 6;
    const int r = lane & 31, g = lane >> 5;
    const int bo = 16 * r + 8 * g;
    const int base_gg = 128 * (wv + 1) + 4 * r + g + 2;   // A-frag group at dd=0

    f32x16 a1, a2, a3;
    #pragma unroll
    for (int i = 0; i < 16; ++i) { a1[i] = 0.f; a2[i] = 0.f; a3[i] = 0.f; }

    const unsigned short* bhp = Bth + bo;
    const unsigned short* blp = Btl + bo;
    bf16x8 bh0 = *(const bf16x8*)(bhp);
    bf16x8 bl0 = *(const bf16x8*)(blp);
    bf16x8 bh1 = *(const bf16x8*)(bhp + 512);
    bf16x8 bl1 = *(const bf16x8*)(blp + 512);

    for (int dd = 0; dd < NBAND; dd += 2) {
        bf16x8 nh0, nl0, nh1, nl1;
        if (dd + 2 < NBAND) {
            nh0 = *(const bf16x8*)(bhp + 512 * (dd + 2));
            nl0 = *(const bf16x8*)(blp + 512 * (dd + 2));
            nh1 = *(const bf16x8*)(bhp + 512 * (dd + 3));
            nl1 = *(const bf16x8*)(blp + 512 * (dd + 3));
        }
        {
            int gg = base_gg - 2 * dd;
            int off = (gg ^ ((gg >> 3) & 7)) << 3;
            bf16x8 avh = *(const bf16x8*)&Ah[off];
            bf16x8 avl = *(const bf16x8*)&Al[off];
            a1 = __builtin_amdgcn_mfma_f32_32x32x16_bf16(avh, bh0, a1, 0, 0, 0);
            a2 = __builtin_amdgcn_mfma_f32_32x32x16_bf16(avl, bh0, a2, 0, 0, 0);
            a3 = __builtin_amdgcn_mfma_f32_32x32x16_bf16(avh, bl0, a3, 0, 0, 0);
        }
        {
            int gg = base_gg - 2 * (dd + 1);
            int off = (gg ^ ((gg >> 3) & 7)) << 3;
            bf16x8 avh = *(const bf16x8*)&Ah[off];
            bf16x8 avl = *(const bf16x8*)&Al[off];
            a1 = __builtin_amdgcn_mfma_f32_32x32x16_bf16(avh, bh1, a1, 0, 0, 0);
            a2 = __builtin_amdgcn_mfma_f32_32x32x16_bf16(avl, bh1, a2, 0, 0, 0);
            a3 = __builtin_amdgcn_mfma_f32_32x32x16_bf16(avh, bl1, a3, 0, 0, 0);
        }
        bh0 = nh0; bl0 = nl0; bh1 = nh1; bl1 = nl1;
    }

    const size_t tb = tb0 + 1024 * wv;
    #pragma unroll
    for (int reg = 0; reg < 16; ++reg) {
        int row = (reg & 3) + 8 * (reg >> 2) + 4 * g;
        fr[tb + 32 * row + r] = f2bf(a1[reg] + a2[reg] + a3[reg]);
    }
}

// ------------------------------------------------------------- MFMA GEMM ----
// D = A(bf16, MxK row-major) @ W(f32, KxN row-major, converted inline).
// 128xBN tile, 4 waves, BK=32, mfma_f32_16x16x32_bf16.
// Software-pipelined (unroll-by-2): global loads stay IN FLIGHT across the
// per-step barrier (raw "s_waitcnt lgkmcnt(0); s_barrier" -- only LDS drained).
// W regs 1 phase deep, A regs 2 phases deep. nsteps must be EVEN.
// 1-D grid with XCD pairing (ids p, p+8 share a W panel on one XCD).
template<int MODE, int RELU, int BN>
__global__ __launch_bounds__(256)
void mfma_gemm(const unsigned short* __restrict__ A, const float* __restrict__ W,
               void* __restrict__ Out, const float* __restrict__ bias,
               int M, int N, int K, int kChunk, int nbn,
               unsigned short* __restrict__ Out2)
{
    constexpr int NE = (BN == 128) ? 8 : 4;   // staged k-rows per thread
    constexpr int N4 = BN / 32;               // B frags per wave
    __shared__ unsigned short Bs[2][BN * 40];
    const int tid = threadIdx.x;
    const int id = blockIdx.x;
    const int gq = id >> 4, rr = id & 15;
    const int t  = gq * 8 + (rr & 7);
    const int bm = (rr >> 3) * 128;
    const int bn = (t % nbn) * BN;
    const int z  = t / nbn;
    const int kb0 = z * kChunk;
    const int nsteps = kChunk >> 5;

    const int lane = tid & 63;
    const int wv = tid >> 6;
    const int wr = (wv >> 1) * 64, wc = (wv & 1) * (BN / 2);
    const int l15 = lane & 15, l4 = lane >> 4;

    const int sn  = (BN == 128) ? (tid & 63) * 2 : (tid & 31) * 2;
    const int skq = (BN == 128) ? (tid >> 6) * 8 : (tid >> 5) * 4;

    f32x4 acc[4][N4];
    #pragma unroll
    for (int i = 0; i < 4; ++i)
        #pragma unroll
        for (int j = 0; j < N4; ++j)
            acc[i][j] = (f32x4){0.f, 0.f, 0.f, 0.f};

    const unsigned short* Arow = A + (size_t)(bm + wr + l15) * K + l4 * 8;
    float2 Rb0[NE], Rb1[NE];
    bf16x8 fa0[4], fa1[4];

#define LOADB(R, kb) { const float* Wp_ = W + (size_t)((kb) + skq) * N + bn + sn;         \
    _Pragma("unroll") for (int e = 0; e < NE; ++e) R[e] = *(const float2*)(Wp_ + (size_t)e * N); }
#define WRITEB(R, b) {                                                                    \
    if (BN == 128) {                                                                      \
        u16x8 p0_, p1_;                                                                   \
        _Pragma("unroll") for (int e = 0; e < NE; ++e) { p0_[e] = f2bf(R[e].x); p1_[e] = f2bf(R[e].y); } \
        *(u16x8*)&Bs[b][sn * 40 + skq]       = p0_;                                       \
        *(u16x8*)&Bs[b][(sn + 1) * 40 + skq] = p1_;                                       \
    } else {                                                                              \
        u16x4 p0_, p1_;                                                                   \
        _Pragma("unroll") for (int e = 0; e < NE; ++e) { p0_[e] = f2bf(R[e].x); p1_[e] = f2bf(R[e].y); } \
        *(u16x4*)&Bs[b][sn * 40 + skq]       = p0_;                                       \
        *(u16x4*)&Bs[b][(sn + 1) * 40 + skq] = p1_;                                       \
    } }
#define LOADA(F, kb) { _Pragma("unroll") for (int m4 = 0; m4 < 4; ++m4)                   \
    F[m4] = *(const bf16x8*)(Arow + (kb) + (size_t)m4 * 16 * K); }
#define RDB(fb, b) { _Pragma("unroll") for (int n4 = 0; n4 < N4; ++n4)                    \
    fb[n4] = *(const bf16x8*)&Bs[b][(wc + n4 * 16 + l15) * 40 + l4 * 8]; }
#define BARRIER_NODRAIN asm volatile("s_waitcnt lgkmcnt(0)\ns_barrier" ::: "memory")
#define MFMA_CL(fa_, fb_) { _Pragma("unroll") for (int m4 = 0; m4 < 4; ++m4)              \
    _Pragma("unroll") for (int n4 = 0; n4 < N4; ++n4)                                     \
        acc[m4][n4] = __builtin_amdgcn_mfma_f32_16x16x32_bf16(fa_[m4], fb_[n4], acc[m4][n4], 0, 0, 0); }

    // prologue (full drain here is fine; one-time)
    LOADB(Rb0, kb0);
    WRITEB(Rb0, 0);
    LOADB(Rb1, kb0 + 32);
    LOADA(fa0, kb0);
    LOADA(fa1, kb0 + 32);
    __syncthreads();

    for (int s = 0; s < nsteps; s += 2) {
        const int kb = kb0 + s * 32;
        {   // even step: compute panel s from Bs[0]; stage panel s+1
            bf16x8 fb[N4], acur[4];
            RDB(fb, 0);
            WRITEB(Rb1, 1);                       // panel s+1 (always exists)
            if (s + 2 < nsteps) LOADB(Rb0, kb + 64);
            #pragma unroll
            for (int m4 = 0; m4 < 4; ++m4) acur[m4] = fa0[m4];
            if (s + 2 < nsteps) LOADA(fa0, kb + 64);
            BARRIER_NODRAIN;
            MFMA_CL(acur, fb);
        }
        {   // odd step: compute panel s+1 from Bs[1]; stage panel s+2
            bf16x8 fb[N4], acur[4];
            RDB(fb, 1);
            if (s + 2 < nsteps) WRITEB(Rb0, 0);
            if (s + 3 < nsteps) LOADB(Rb1, kb + 96);
            #pragma unroll
            for (int m4 = 0; m4 < 4; ++m4) acur[m4] = fa1[m4];
            if (s + 3 < nsteps) LOADA(fa1, kb + 96);
            BARRIER_NODRAIN;
            MFMA_CL(acur, fb);
        }
    }
#undef LOADB
#undef WRITEB
#undef LOADA
#undef RDB
#undef BARRIER_NODRAIN
#undef MFMA_CL

    #pragma unroll
    for (int m4 = 0; m4 < 4; ++m4)
        #pragma unroll
        for (int n4 = 0; n4 < N4; ++n4) {
            const int col = bn + wc + n4 * 16 + l15;
            const int row0 = bm + wr + m4 * 16 + l4 * 4;
            #pragma unroll
            for (int rg = 0; rg < 4; ++rg) {
                float v = acc[m4][n4][rg];
                const size_t oi = (size_t)(row0 + rg) * N + col;
                if (MODE == 0) {
                    ((float*)Out)[(size_t)z * M * N + oi] = v;
                } else {
                    v += bias[col];
                    if (RELU) v = fmaxf(v, 0.f);
                    if (MODE == 1) {
                        ((float*)Out)[oi] = v;
                    } else if (MODE == 2) {
                        ((unsigned short*)Out)[oi] = f2bf(v);
                    } else {
                        unsigned short h, l; split2(v, h, l);
                        ((unsigned short*)Out)[oi] = h; Out2[oi] = l;
                    }
                }
            }
        }
}

// --------------------------------------------------------------- reduce -----
template<int RELU, int OUTBF>
__global__ __launch_bounds__(256)
void reduce_bias(const float* __restrict__ P, const float* __restrict__ bias,
                 void* __restrict__ C, int MN, int N, int S)
{
    const int idx4 = blockIdx.x * 256 + threadIdx.x;
    const int MN4 = MN >> 2;
    if (idx4 >= MN4) return;
    const float4* P4 = (const float4*)P;
    float4 a = P4[idx4];
    for (int zz = 1; zz < S; ++zz) {
        float4 b = P4[(size_t)zz * MN4 + idx4];
        a.x += b.x; a.y += b.y; a.z += b.z; a.w += b.w;
    }
    int n0 = (idx4 * 4) % N;
    a.x += bias[n0]; a.y += bias[n0 + 1]; a.z += bias[n0 + 2]; a.w += bias[n0 + 3];
    if (RELU) {
        a.x = fmaxf(a.x, 0.f); a.y = fmaxf(a.y, 0.f);
        a.z = fmaxf(a.z, 0.f); a.w = fmaxf(a.w, 0.f);
    }
    if (OUTBF) {
        ushort4 v = {f2bf(a.x), f2bf(a.y), f2bf(a.z), f2bf(a.w)};
        ((ushort4*)C)[idx4] = v;
    } else {
        ((float4*)C)[idx4] = a;
    }
}

// ---------------------------------------------------------------- launch ----
extern "C" void kernel_launch(void* const* d_in, const int* in_sizes, int n_in,
                              void* d_out, int out_size, void* d_ws, size_t ws_size,
                              hipStream_t stream)
{
    const float* x   = (const float*)d_in[0];
    const float* Ws1 = (const float*)d_in[1];
    const float* bs1 = (const float*)d_in[2];
    const float* Ws2 = (const float*)d_in[3];
    const float* bs2 = (const float*)d_in[4];
    const float* Wn1 = (const float*)d_in[5];
    const float* bn1 = (const float*)d_in[6];
    const float* Wn2 = (const float*)d_in[7];
    const float* bn2 = (const float*)d_in[8];
    const float* Wn3 = (const float*)d_in[9];
    const float* bn3 = (const float*)d_in[10];
    float* out = (float*)d_out;

    char* p = (char*)d_ws;
    auto alloc = [&](size_t bytes) { char* q = p; p += (bytes + 255) & ~(size_t)255; return q; };
    unsigned short* Tch = (unsigned short*)alloc(8192);
    unsigned short* Tcl = (unsigned short*)alloc(8192);
    unsigned short* Tsh = (unsigned short*)alloc(8192);
    unsigned short* Tsl = (unsigned short*)alloc(8192);
    unsigned short* Bth = (unsigned short*)alloc((size_t)NBAND * 512 * 2);
    unsigned short* Btl = (unsigned short*)alloc((size_t)NBAND * 512 * 2);
    unsigned short* fhb = (unsigned short*)alloc((size_t)(1024 + NTOT) * 2);
    unsigned short* flb = (unsigned short*)alloc((size_t)(1024 + NTOT) * 2);
    unsigned short* fr   = (unsigned short*)alloc((size_t)NTOT * 2);
    unsigned short* spec = (unsigned short*)alloc((size_t)NTOT * 2);
    unsigned short* ph   = (unsigned short*)alloc((size_t)NTOT * 2);
    unsigned short* pl   = (unsigned short*)alloc((size_t)NTOT * 2);
    unsigned short* t1   = (unsigned short*)alloc(262144);
    unsigned short* h1   = (unsigned short*)alloc(262144);
    unsigned short* h2   = (unsigned short*)alloc(262144);
    float* part          = (float*)alloc((size_t)16 * 131072 * 4);

    gen_tables<<<8, 1024, 0, stream>>>(Tch, Tcl, Tsh, Tsl, Bth, Btl, fhb, flb);

    // forward fft2 real part -> hi/lo bf16 f (offset 1024, zero prefix)
    dft_mfma<0><<<NIMG, 256, 0, stream>>>(x, nullptr, Tch, Tcl, Tsh, Tsl,
                                          fhb + 1024, flb + 1024);

    // GL fractional conv (banded block-GEMM, LDS-staged A) -> fr (bf16)
    conv_mfma<<<NTOT / 4096, 256, 0, stream>>>(fhb + 1024, flb + 1024, Bth, Btl, fr);

    // spectral_operator: L1 (split-K z=16) + reduce, L2 (N=12288)
    mfma_gemm<0, 0, 64><<<256, 256, 0, stream>>>(fr, Ws1, part, nullptr,
                                                 256, 512, 12288, 768, 8, nullptr);
    reduce_bias<1, 1><<<128, 256, 0, stream>>>(part, bs1, t1, 131072, 512, 16);
    mfma_gemm<2, 0, 64><<<384, 256, 0, stream>>>(t1, Ws2, spec, bs2,
                                                 256, 12288, 512, 512, 192, nullptr);

    // neural_operator: L3 + reduce, L4 (z=8) + reduce, L5 (N=12288, hi/lo out)
    mfma_gemm<0, 0, 64><<<256, 256, 0, stream>>>(spec, Wn1, part, nullptr,
                                                 256, 512, 12288, 768, 8, nullptr);
    reduce_bias<1, 1><<<128, 256, 0, stream>>>(part, bn1, h1, 131072, 512, 16);
    mfma_gemm<0, 0, 64><<<128, 256, 0, stream>>>(h1, Wn2, part, nullptr,
                                                 256, 512, 512, 64, 8, nullptr);
    reduce_bias<1, 1><<<128, 256, 0, stream>>>(part, bn2, h2, 131072, 512, 8);
    mfma_gemm<3, 0, 64><<<384, 256, 0, stream>>>(h2, Wn3, ph, bn3,
                                                 256, 12288, 512, 512, 192, pl);

    // inverse fft2 real part (hi/lo bf16 in, f32 out, scale 1/4096)
    dft_mfma<1><<<NIMG, 256, 0, stream>>>(ph, pl, Tch, Tcl, Tsh, Tsl, out, nullptr);
}